// Round 4
// baseline (6821.859 us; speedup 1.0000x reference)
//
#include <hip/hip_runtime.h>
#include <cstdint>
#include <cmath>

#define V 32000
#define E 512
#define H 1024
#define B 128
#define S 64
#define NCHUNK 8
#define CHUNK 4000       // V / NCHUNK (fallback sampling path)
#define PSTRIDE 250      // partial-array stride: max chunks (mfma fused path: 250)
#define BS (B*S)
#define NEG_HUGE (-3.0e38f)

typedef __attribute__((ext_vector_type(8))) short short8;
typedef __attribute__((ext_vector_type(4))) float f32x4;

// ---------------- threefry2x32 (JAX-exact, 20 rounds) ----------------
#define TFR(x0, x1, r) { x0 += x1; x1 = ((x1) << (r)) | ((x1) >> (32 - (r))); x1 ^= x0; }

__host__ __device__ inline void tf2x32(uint32_t k0, uint32_t k1, uint32_t &x0, uint32_t &x1) {
  uint32_t ks2 = k0 ^ k1 ^ 0x1BD11BDAu;
  x0 += k0; x1 += k1;
  TFR(x0,x1,13) TFR(x0,x1,15) TFR(x0,x1,26) TFR(x0,x1,6)
  x0 += k1;  x1 += ks2 + 1u;
  TFR(x0,x1,17) TFR(x0,x1,29) TFR(x0,x1,16) TFR(x0,x1,24)
  x0 += ks2; x1 += k0 + 2u;
  TFR(x0,x1,13) TFR(x0,x1,15) TFR(x0,x1,26) TFR(x0,x1,6)
  x0 += k0;  x1 += k1 + 3u;
  TFR(x0,x1,17) TFR(x0,x1,29) TFR(x0,x1,16) TFR(x0,x1,24)
  x0 += k1;  x1 += ks2 + 4u;
  TFR(x0,x1,13) TFR(x0,x1,15) TFR(x0,x1,26) TFR(x0,x1,6)
  x0 += ks2; x1 += k0 + 5u;
}

// partitionable threefry 32-bit bits: xor of both output words of enc(hi=0, lo=i)
__device__ __forceinline__ uint32_t tf_bits32(uint32_t ka, uint32_t kb, uint32_t idx) {
  uint32_t x0 = 0u, x1 = idx;
  tf2x32(ka, kb, x0, x1);
  return x0 ^ x1;
}

__device__ __forceinline__ float bits_to_unif(uint32_t b) {
  return __uint_as_float((b >> 9) | 0x3f800000u) - 1.0f;
}

__device__ __forceinline__ float sigmoidf_(float x) { return 1.0f / (1.0f + expf(-x)); }

// bf16 round-to-nearest-even helpers
__device__ __forceinline__ ushort f2bf(float f) {
  uint32_t u = __float_as_uint(f);
  uint32_t r = u + 0x7FFFu + ((u >> 16) & 1u);
  return (ushort)(r >> 16);
}
__device__ __forceinline__ float bf2f(ushort h) { return __uint_as_float(((uint32_t)h) << 16); }

// async global->LDS, 16 B per lane. LDS dest = wave-uniform base + lane*16.
__device__ __forceinline__ void gload16(const ushort* g, ushort* l) {
  __builtin_amdgcn_global_load_lds((const __attribute__((address_space(1))) void*)g,
                                   (__attribute__((address_space(3))) void*)l, 16, 0, 0);
}

// ---------------- f32 GEMM tile (fallback paths only) ----------------
template<int BM, int BN, int BK, int TM, int TN>
__device__ void gemm_tile(const float* __restrict__ A, const float* __restrict__ Wt,
                          const float* __restrict__ bias, float* __restrict__ C,
                          int N, int K, int mblk, int nblk)
{
  constexpr int WP = BN + 4;
  __shared__ __align__(16) float As[BK][BM];
  __shared__ __align__(16) float Ws[BK][WP];
  const int tid = threadIdx.x;
  constexpr int TX = BN / TN;
  constexpr int TY = BM / TM;
  static_assert(TX * TY == 256, "bad tiling");
  const int tx = tid % TX, ty = tid / TX;
  const int n0 = tx * TN, m0 = ty * TM;

  float acc[TM][TN];
#pragma unroll
  for (int i = 0; i < TM; ++i)
#pragma unroll
    for (int j = 0; j < TN; ++j) acc[i][j] = 0.0f;

  constexpr int NA = (BM * BK / 4) / 256;
  constexpr int NW = (BN * BK / 4) / 256;
  static_assert(NA >= 1 && NW >= 1, "tile too small");

  for (int k0 = 0; k0 < K; k0 += BK) {
    __syncthreads();
#pragma unroll
    for (int q = 0; q < NA; ++q) {
      int idx = q * 256 + tid;
      int m = idx / (BK / 4), c = idx % (BK / 4);
      float4 v = *(const float4*)&A[(size_t)(mblk + m) * K + k0 + 4 * c];
      As[4*c+0][m] = v.x; As[4*c+1][m] = v.y; As[4*c+2][m] = v.z; As[4*c+3][m] = v.w;
    }
#pragma unroll
    for (int q = 0; q < NW; ++q) {
      int idx = q * 256 + tid;
      int n = idx / (BK / 4), c = idx % (BK / 4);
      float4 v = *(const float4*)&Wt[(size_t)(nblk + n) * K + k0 + 4 * c];
      Ws[4*c+0][n] = v.x; Ws[4*c+1][n] = v.y; Ws[4*c+2][n] = v.z; Ws[4*c+3][n] = v.w;
    }
    __syncthreads();
#pragma unroll
    for (int k = 0; k < BK; ++k) {
      float a[TM], w[TN];
#pragma unroll
      for (int i = 0; i < TM; ++i) a[i] = As[k][m0 + i];
#pragma unroll
      for (int j = 0; j < TN; ++j) w[j] = Ws[k][n0 + j];
#pragma unroll
      for (int i = 0; i < TM; ++i)
#pragma unroll
        for (int j = 0; j < TN; ++j) acc[i][j] += a[i] * w[j];
    }
  }
#pragma unroll
  for (int i = 0; i < TM; ++i)
#pragma unroll
    for (int j = 0; j < TN; ++j)
      C[(size_t)(mblk + m0 + i) * N + nblk + n0 + j] = acc[i][j] + bias[nblk + n0 + j];
}

// fallback dist GEMM (f32)
__global__ __launch_bounds__(256) void gemm_dist_k(const float* __restrict__ h,
    const float* __restrict__ w_dist, const float* __restrict__ b_dist,
    float* __restrict__ logits)
{
  gemm_tile<128, 64, 16, 8, 4>(h, w_dist, b_dist, logits, V, H, 0, blockIdx.x * 64);
}

// fallback GRU gemms (f32)
__global__ __launch_bounds__(256) void gemm_gru_k(const float* __restrict__ x,
    const float* __restrict__ h, const float* __restrict__ w_ih, const float* __restrict__ w_hh,
    const float* __restrict__ b_ih, const float* __restrict__ b_hh,
    float* __restrict__ gx, float* __restrict__ gh)
{
  int b = blockIdx.x;
  if (b < 96) {
    int rb = b & 1, cb = b >> 1;
    gemm_tile<64, 64, 16, 4, 4>(x, w_ih, b_ih, gx, 3 * H, E, rb * 64, cb * 64);
  } else {
    b -= 96;
    int rb = b & 1, cb = b >> 1;
    gemm_tile<64, 64, 16, 4, 4>(h, w_hh, b_hh, gh, 3 * H, H, rb * 64, cb * 64);
  }
}

// split f32 -> bf16 hi/lo (dist weights only, once per call)
__global__ __launch_bounds__(256) void wsplit_k(const float* __restrict__ w,
    ushort* __restrict__ whi, ushort* __restrict__ wlo, int n4)
{
  int idx = blockIdx.x * 256 + threadIdx.x;
  if (idx >= n4) return;
  size_t i = (size_t)idx * 4;
  float4 v = *(const float4*)&w[i];
  ushort h0 = f2bf(v.x), h1 = f2bf(v.y), h2 = f2bf(v.z), h3 = f2bf(v.w);
  ushort l0 = f2bf(v.x - bf2f(h0)), l1 = f2bf(v.y - bf2f(h1));
  ushort l2 = f2bf(v.z - bf2f(h2)), l3 = f2bf(v.w - bf2f(h3));
  ushort4 hv = {h0, h1, h2, h3}, lv = {l0, l1, l2, l3};
  *(ushort4*)&whi[i] = hv;
  *(ushort4*)&wlo[i] = lv;
}

// GRU gates, h updated in place; also emits bf16 hi/lo split of h
__global__ __launch_bounds__(256) void gru_gates_k(const float* __restrict__ gx,
    const float* __restrict__ gh, float* __restrict__ h,
    ushort* __restrict__ hhi, ushort* __restrict__ hlo)
{
  int idx = blockIdx.x * 256 + threadIdx.x;   // B*H = 131072
  int b = idx >> 10, j = idx & 1023;
  const float* gxb = gx + (size_t)b * 3 * H;
  const float* ghb = gh + (size_t)b * 3 * H;
  float r = sigmoidf_(gxb[j] + ghb[j]);
  float z = sigmoidf_(gxb[H + j] + ghb[H + j]);
  float n = tanhf(gxb[2 * H + j] + r * ghb[2 * H + j]);
  float hn = (1.0f - z) * n + z * h[idx];
  h[idx] = hn;
  ushort hi = f2bf(hn);
  hhi[idx] = hi;
  hlo[idx] = f2bf(hn - bf2f(hi));
}

// ---------------- MFMA bf16x3 dist GEMM with FUSED sampling partials ----------------
// (unchanged from verified R3 kernel)
__global__ __launch_bounds__(512) void gemm_dist_mfma(const ushort* __restrict__ hhi,
    const ushort* __restrict__ hlo, const ushort* __restrict__ whi,
    const ushort* __restrict__ wlo, const float* __restrict__ b_dist,
    float* __restrict__ logits,
    float* __restrict__ pm, float* __restrict__ ps,
    float* __restrict__ pbest, int* __restrict__ pidx,
    uint32_t k1a, uint32_t k1b, uint32_t k2a, uint32_t k2b)
{
  __shared__ ushort Ah[2][128 * 32], Al[2][128 * 32], Wh[2][128 * 32], Wl[2][128 * 32];
  __shared__ float rm[2 * 128], rs[2 * 128], rb_[2 * 128];
  __shared__ int   ri[2 * 128];
  __shared__ uint32_t sdraw[128];
  const int tid = threadIdx.x;
  const int wave = tid >> 6, lane = tid & 63;
  const int wm = (wave & 3) * 32;
  const int wn = (wave >> 2) * 64;
  const int nblk = blockIdx.x * 128;
  const int l15 = lane & 15;
  const int q = lane >> 4;

  if (tid < 128)
    sdraw[tid] = (bits_to_unif(tf_bits32(k1a, k1b, (uint32_t)tid)) <= 0.05f) ? 1u : 0u;

  const int sr = tid >> 2;
  const int gq8 = ((tid & 3) ^ ((sr >> 1) & 3)) * 8;
  const size_t arow = (size_t)sr * 1024 + gq8;
  const size_t wrow = (size_t)(nblk + sr) * 1024 + gq8;
  const int wbase = wave * 512;

#define DIST_STAGE(bf, kk) {                                   \
    gload16(&hhi[arow + (kk)], &Ah[bf][wbase]);                \
    gload16(&hlo[arow + (kk)], &Al[bf][wbase]);                \
    gload16(&whi[wrow + (kk)], &Wh[bf][wbase]);                \
    gload16(&wlo[wrow + (kk)], &Wl[bf][wbase]);                \
  }

  f32x4 acc[2][4] = {};

  DIST_STAGE(0, 0);
  asm volatile("s_waitcnt vmcnt(0)" ::: "memory");
  __builtin_amdgcn_sched_barrier(0);
  __builtin_amdgcn_s_barrier();

  int buf = 0;
  for (int k0 = 0; k0 < 1024; k0 += 32, buf ^= 1) {
    if (k0 + 32 < 1024) DIST_STAGE(buf ^ 1, k0 + 32);

    short8 ah[2], al[2], wh[4], wl[4];
#pragma unroll
    for (int mt = 0; mt < 2; ++mt) {
      int row = wm + mt * 16 + l15;
      int off = row * 32 + ((q ^ ((row >> 1) & 3)) * 8);
      ah[mt] = *(const short8*)&Ah[buf][off];
      al[mt] = *(const short8*)&Al[buf][off];
    }
#pragma unroll
    for (int nt = 0; nt < 4; ++nt) {
      int row = wn + nt * 16 + l15;
      int off = row * 32 + ((q ^ ((row >> 1) & 3)) * 8);
      wh[nt] = *(const short8*)&Wh[buf][off];
      wl[nt] = *(const short8*)&Wl[buf][off];
    }
#pragma unroll
    for (int mt = 0; mt < 2; ++mt)
#pragma unroll
      for (int nt = 0; nt < 4; ++nt) {
        acc[mt][nt] = __builtin_amdgcn_mfma_f32_16x16x32_bf16(ah[mt], wh[nt], acc[mt][nt], 0, 0, 0);
        acc[mt][nt] = __builtin_amdgcn_mfma_f32_16x16x32_bf16(al[mt], wh[nt], acc[mt][nt], 0, 0, 0);
        acc[mt][nt] = __builtin_amdgcn_mfma_f32_16x16x32_bf16(ah[mt], wl[nt], acc[mt][nt], 0, 0, 0);
      }

    asm volatile("s_waitcnt vmcnt(0)" ::: "memory");
    __builtin_amdgcn_sched_barrier(0);
    __builtin_amdgcn_s_barrier();
  }
#undef DIST_STAGE

  float bv[4];
#pragma unroll
  for (int nt = 0; nt < 4; ++nt) bv[nt] = b_dist[nblk + wn + nt * 16 + l15];

  const float LOGU = -logf((float)V);
#pragma unroll
  for (int mt = 0; mt < 2; ++mt) {
#pragma unroll
    for (int reg = 0; reg < 4; ++reg) {
      const int r = wm + mt * 16 + q * 4 + reg;     // batch row
      const bool draw = sdraw[r] != 0u;
      float m0 = NEG_HUGE, s0 = 0.0f, best = NEG_HUGE;
      int bi = 2147483647;
#pragma unroll
      for (int nt = 0; nt < 4; ++nt) {
        const int col = nblk + wn + nt * 16 + l15;
        float a = acc[mt][nt][reg] + bv[nt];
        logits[(size_t)r * V + col] = a;
        if (a > m0) { s0 = s0 * expf(m0 - a) + 1.0f; m0 = a; } else { s0 += expf(a - m0); }
        uint32_t bits = tf_bits32(k2a, k2b, (uint32_t)(r * V + col));
        float g = -logf(-logf(bits_to_unif(bits)));
        float key = draw ? (LOGU + g) : (a + g);
        if (key > best) { best = key; bi = col; }
      }
#pragma unroll
      for (int off = 1; off < 16; off <<= 1) {
        float mo = __shfl_xor(m0, off);
        float so = __shfl_xor(s0, off);
        float M = fmaxf(m0, mo);
        s0 = s0 * expf(m0 - M) + so * expf(mo - M);
        m0 = M;
        float bo = __shfl_xor(best, off);
        int io = __shfl_xor(bi, off);
        if (bo > best || (bo == best && io < bi)) { best = bo; bi = io; }
      }
      if (l15 == 0) {
        const int slot = (wave >> 2) * 128 + r;
        rm[slot] = m0; rs[slot] = s0; rb_[slot] = best; ri[slot] = bi;
      }
    }
  }
  __syncthreads();
  if (tid < 128) {
    float ma = rm[tid], sa = rs[tid], mb = rm[128 + tid], sb = rs[128 + tid];
    float M = fmaxf(ma, mb);
    float s = sa * expf(ma - M) + sb * expf(mb - M);
    pm[tid * PSTRIDE + blockIdx.x] = M;
    ps[tid * PSTRIDE + blockIdx.x] = s;
    float va = rb_[tid], vb = rb_[128 + tid];
    int ia = ri[tid], ib = ri[128 + tid];
    if (vb > va || (vb == va && ib < ia)) { va = vb; ia = ib; }
    pbest[tid * PSTRIDE + blockIdx.x] = va;
    pidx[tid * PSTRIDE + blockIdx.x] = ia;
  }
}

// ---------------- MFMA bf16x3 64x64-tile GRU GEMM, W from f32 ----------------
// A-side: pre-split bf16 hi/lo arrays (xhi/xlo or hhi/hlo). W-side: staged directly
// from the f32 weight matrix via global_load_lds (no persistent split arrays ->
// need_gru == need of small arrays only, so the MFMA path activates whenever the
// dist path does). W tile [64][32] f32 staged with 16B-position XOR swizzle
// p_stored = p_logical ^ (row&7) (2-way bank alias only = free). Fragment read
// converts f32 -> bf16 hi/lo in registers with the SAME f2bf math as wsplit_k,
// so results are bit-identical to the previous split-array kernel.
__device__ void gemm64_wf32(const ushort* __restrict__ Ahi_g, const ushort* __restrict__ Alo_g,
    const float* __restrict__ Wg, const float* __restrict__ bias, float* __restrict__ C,
    int N, int K, int mblk, int nblk)
{
  __shared__ ushort Ah[2][64 * 32], Al[2][64 * 32];
  __shared__ float  Wf[2][64 * 32];
  const int tid = threadIdx.x;
  const int wave = tid >> 6, lane = tid & 63;
  const int wm = (wave & 1) * 32, wn = (wave >> 1) * 32;
  const int l15 = lane & 15, q = lane >> 4;

  // A staging: 256 segs (64 rows x 4 quads), 1 seg/thread per array; quad-XOR source
  const int sr = tid >> 2;
  const int ga = ((tid & 3) ^ ((sr >> 1) & 3)) * 8;
  const size_t aoff = (size_t)(mblk + sr) * K + ga;
  // W staging: 512 segs (64 rows x 8 f32-quads), 2 segs/thread; pos-XOR source
  const int s1 = 256 + tid;
  const int wr0 = tid >> 3, wp0 = tid & 7;
  const int wr1 = s1 >> 3,  wp1 = s1 & 7;
  const size_t woff0 = (size_t)(nblk + wr0) * K + (wp0 ^ (wr0 & 7)) * 4;
  const size_t woff1 = (size_t)(nblk + wr1) * K + (wp1 ^ (wr1 & 7)) * 4;
  const int abase  = wave * 512;          // ushort idx
  const int wbase0 = wave * 256;          // float idx
  const int wbase1 = 1024 + wave * 256;   // float idx

#define GRU_STAGE(bf, kk) {                                            \
    gload16(&Ahi_g[aoff + (kk)], &Ah[bf][abase]);                      \
    gload16(&Alo_g[aoff + (kk)], &Al[bf][abase]);                      \
    gload16((const ushort*)&Wg[woff0 + (kk)], (ushort*)&Wf[bf][wbase0]); \
    gload16((const ushort*)&Wg[woff1 + (kk)], (ushort*)&Wf[bf][wbase1]); \
  }

  f32x4 acc[2][2] = {};

  GRU_STAGE(0, 0);
  asm volatile("s_waitcnt vmcnt(0)" ::: "memory");
  __builtin_amdgcn_sched_barrier(0);
  __builtin_amdgcn_s_barrier();

  int buf = 0;
  for (int k0 = 0; k0 < K; k0 += 32, buf ^= 1) {
    if (k0 + 32 < K) GRU_STAGE(buf ^ 1, k0 + 32);

    short8 ah[2], al[2], wh[2], wl[2];
#pragma unroll
    for (int mt = 0; mt < 2; ++mt) {
      int row = wm + mt * 16 + l15;
      int off = row * 32 + ((q ^ ((row >> 1) & 3)) * 8);
      ah[mt] = *(const short8*)&Ah[buf][off];
      al[mt] = *(const short8*)&Al[buf][off];
    }
#pragma unroll
    for (int nt = 0; nt < 2; ++nt) {
      int row = wn + nt * 16 + l15;
      int base = row * 32;
      float4 f0 = *(const float4*)&Wf[buf][base + (((2 * q + 0) ^ (row & 7)) * 4)];
      float4 f1 = *(const float4*)&Wf[buf][base + (((2 * q + 1) ^ (row & 7)) * 4)];
      float fv[8] = {f0.x, f0.y, f0.z, f0.w, f1.x, f1.y, f1.z, f1.w};
      short8 hi, lo;
#pragma unroll
      for (int j = 0; j < 8; ++j) {
        ushort hb = f2bf(fv[j]);
        hi[j] = (short)hb;
        lo[j] = (short)f2bf(fv[j] - bf2f(hb));
      }
      wh[nt] = hi; wl[nt] = lo;
    }
#pragma unroll
    for (int mt = 0; mt < 2; ++mt)
#pragma unroll
      for (int nt = 0; nt < 2; ++nt) {
        acc[mt][nt] = __builtin_amdgcn_mfma_f32_16x16x32_bf16(ah[mt], wh[nt], acc[mt][nt], 0, 0, 0);
        acc[mt][nt] = __builtin_amdgcn_mfma_f32_16x16x32_bf16(al[mt], wh[nt], acc[mt][nt], 0, 0, 0);
        acc[mt][nt] = __builtin_amdgcn_mfma_f32_16x16x32_bf16(ah[mt], wl[nt], acc[mt][nt], 0, 0, 0);
      }

    asm volatile("s_waitcnt vmcnt(0)" ::: "memory");
    __builtin_amdgcn_sched_barrier(0);
    __builtin_amdgcn_s_barrier();
  }
#undef GRU_STAGE

#pragma unroll
  for (int nt = 0; nt < 2; ++nt) {
    int col = nblk + wn + nt * 16 + l15;
    float bvv = bias[col];
#pragma unroll
    for (int mt = 0; mt < 2; ++mt) {
      int rbase = mblk + wm + mt * 16 + (lane >> 4) * 4;
#pragma unroll
      for (int reg = 0; reg < 4; ++reg)
        C[(size_t)(rbase + reg) * N + col] = acc[mt][nt][reg] + bvv;
    }
  }
}

// one dispatch for gx (blocks 0..95) + gh (blocks 96..191)
__global__ __launch_bounds__(256) void gemm_gru_mfma(
    const ushort* __restrict__ xhi, const ushort* __restrict__ xlo,
    const ushort* __restrict__ hhi, const ushort* __restrict__ hlo,
    const float* __restrict__ w_ih, const float* __restrict__ w_hh,
    const float* __restrict__ b_ih, const float* __restrict__ b_hh,
    float* __restrict__ gx, float* __restrict__ gh)
{
  int b = blockIdx.x;
  if (b < 96) {
    int mblk = (b & 1) * 64, nblk = (b >> 1) * 64;
    gemm64_wf32(xhi, xlo, w_ih, b_ih, gx, 3 * H, E, mblk, nblk);
  } else {
    b -= 96;
    int mblk = (b & 1) * 64, nblk = (b >> 1) * 64;
    gemm64_wf32(hhi, hlo, w_hh, b_hh, gh, 3 * H, H, mblk, nblk);
  }
}

// init: h = 0 (and its bf16 splits), x = broadcast emb[0] (and its bf16 splits)
__global__ __launch_bounds__(256) void init_k(const float* __restrict__ emb,
    float* __restrict__ h, float* __restrict__ x,
    ushort* __restrict__ hhi, ushort* __restrict__ hlo,
    ushort* __restrict__ xhi, ushort* __restrict__ xlo)
{
  int i = blockIdx.x * 256 + threadIdx.x;   // grid covers B*H
  if (i < B * H) { h[i] = 0.0f; hhi[i] = 0; hlo[i] = 0; }
  if (i < B * E) {
    float v = emb[i & (E - 1)];
    x[i] = v;
    ushort hi = f2bf(v);
    xhi[i] = hi;
    xlo[i] = f2bf(v - bf2f(hi));
  }
}

// fallback pass (f32 dist path only)
__global__ __launch_bounds__(256) void sample_partial_k(const float* __restrict__ logits,
    float* __restrict__ pm, float* __restrict__ ps,
    float* __restrict__ pbest, int* __restrict__ pidx,
    uint32_t k1a, uint32_t k1b, uint32_t k2a, uint32_t k2b)
{
  const int b = blockIdx.x & 127, chunk = blockIdx.x >> 7;
  const int tid = threadIdx.x;
  const bool draw = bits_to_unif(tf_bits32(k1a, k1b, (uint32_t)b)) <= 0.05f;
  const float LOGU = -logf((float)V);
  const int vbeg = chunk * CHUNK, vend = vbeg + CHUNK;
  float m0 = -INFINITY, s0 = 0.0f, best = -INFINITY;
  int bi = 2147483647;
  for (int v = vbeg + tid; v < vend; v += 256) {
    float a = logits[(size_t)b * V + v];
    if (a > m0) { s0 = s0 * expf(m0 - a) + 1.0f; m0 = a; } else { s0 += expf(a - m0); }
    uint32_t bits = tf_bits32(k2a, k2b, (uint32_t)(b * V + v));
    float g = -logf(-logf(bits_to_unif(bits)));
    float key = draw ? (LOGU + g) : (a + g);
    if (key > best) { best = key; bi = v; }
  }
  __shared__ float shm[256], shs[256], sv[256];
  __shared__ int si[256];
  shm[tid] = m0; shs[tid] = s0; sv[tid] = best; si[tid] = bi;
  __syncthreads();
  for (int off = 128; off > 0; off >>= 1) {
    if (tid < off) {
      float ma = shm[tid], sa = shs[tid];
      float mb = shm[tid + off], sb = shs[tid + off];
      float M = fmaxf(ma, mb);
      shm[tid] = M;
      shs[tid] = sa * expf(ma - M) + sb * expf(mb - M);
      float va = sv[tid], vb = sv[tid + off];
      int ia = si[tid], ib = si[tid + off];
      if (vb > va || (vb == va && ib < ia)) { sv[tid] = vb; si[tid] = ib; }
    }
    __syncthreads();
  }
  if (tid == 0) {
    pm[b * PSTRIDE + chunk] = shm[0]; ps[b * PSTRIDE + chunk] = shs[0];
    pbest[b * PSTRIDE + chunk] = sv[0]; pidx[b * PSTRIDE + chunk] = si[0];
  }
}

// fused final: block b = row b, 128 threads
__global__ __launch_bounds__(128) void sample_final_gather_k(const float* __restrict__ logits,
    const float* __restrict__ pm, const float* __restrict__ ps,
    const float* __restrict__ pbest, const int* __restrict__ pidx,
    float* __restrict__ rowm, float* __restrict__ rowz, int* __restrict__ samp,
    const float* __restrict__ emb, float* __restrict__ x,
    ushort* __restrict__ xhi, ushort* __restrict__ xlo,
    float* __restrict__ out, int t, uint32_t k1a, uint32_t k1b, int nchunk)
{
  __shared__ float shm[128], shs[128], shb[128];
  __shared__ int shi[128];
  __shared__ int sh_idx;
  const int b = blockIdx.x, tid = threadIdx.x;
  float m0 = NEG_HUGE, s0 = 0.0f, best = NEG_HUGE;
  int bi = 2147483647;
  for (int c = tid; c < nchunk; c += 128) {
    float ma = pm[b * PSTRIDE + c], sa = ps[b * PSTRIDE + c];
    float M = fmaxf(m0, ma);
    s0 = s0 * expf(m0 - M) + sa * expf(ma - M);
    m0 = M;
    float v = pbest[b * PSTRIDE + c];
    int ix = pidx[b * PSTRIDE + c];
    if (v > best || (v == best && ix < bi)) { best = v; bi = ix; }
  }
  shm[tid] = m0; shs[tid] = s0; shb[tid] = best; shi[tid] = bi;
  __syncthreads();
  for (int off = 64; off > 0; off >>= 1) {
    if (tid < off) {
      float ma = shm[tid], sa = shs[tid];
      float mb = shm[tid + off], sb = shs[tid + off];
      float M = fmaxf(ma, mb);
      shm[tid] = M;
      shs[tid] = sa * expf(ma - M) + sb * expf(mb - M);
      float va = shb[tid], vb = shb[tid + off];
      int ia = shi[tid], ib = shi[tid + off];
      if (vb > va || (vb == va && ib < ia)) { shb[tid] = vb; shi[tid] = ib; }
    }
    __syncthreads();
  }
  if (tid == 0) {
    float mrow = shm[0];
    float z0 = logf(shs[0]);
    int idx = shi[0];
    rowm[b] = mrow; rowz[b] = z0;
    float lp = (logits[(size_t)b * V + idx] - mrow) - z0;
    bool draw = bits_to_unif(tf_bits32(k1a, k1b, (uint32_t)b)) <= 0.05f;
    float corr = 1.0f;
    if (draw) {
      const float LOGU = -logf((float)V);
      float onp = fminf(fmaxf(expf(lp), 1e-8f), 1.0f);
      float offp = fminf(fmaxf(expf(LOGU), 1e-8f), 1.0f);
      corr = onp / offp;
    }
    out[b * S + t] = (float)idx;
    out[BS + b * S + t] = corr;
    out[2 * BS + b * S + t] = lp;
    samp[b] = idx;
    sh_idx = idx;
  }
  __syncthreads();
  const int row = sh_idx;
  float4 v = *(const float4*)&emb[(size_t)row * E + tid * 4];
  *(float4*)&x[(size_t)b * E + tid * 4] = v;
  ushort h0 = f2bf(v.x), h1 = f2bf(v.y), h2 = f2bf(v.z), h3 = f2bf(v.w);
  ushort l0 = f2bf(v.x - bf2f(h0)), l1 = f2bf(v.y - bf2f(h1));
  ushort l2 = f2bf(v.z - bf2f(h2)), l3 = f2bf(v.w - bf2f(h3));
  ushort4 hv = {h0, h1, h2, h3}, lv = {l0, l1, l2, l3};
  *(ushort4*)&xhi[(size_t)b * E + tid * 4] = hv;
  *(ushort4*)&xlo[(size_t)b * E + tid * 4] = lv;
}

// probs[t, v] = mean_b exp(dist[b, v])
__global__ __launch_bounds__(256) void probs_k(const float* __restrict__ logits,
    const float* __restrict__ rowm, const float* __restrict__ rowz,
    float* __restrict__ out, int t)
{
  __shared__ float sm[B], sz[B];
  __shared__ float red[256];
  const int tid = threadIdx.x;
  if (tid < B) { sm[tid] = rowm[tid]; sz[tid] = rowz[tid]; }
  __syncthreads();
  const int v = blockIdx.x * 64 + (tid & 63);
  const int bh = tid >> 6;
  float acc = 0.0f;
#pragma unroll 4
  for (int i = 0; i < 32; ++i) {
    int b = bh * 32 + i;
    acc += expf((logits[(size_t)b * V + v] - sm[b]) - sz[b]);
  }
  red[tid] = acc;
  __syncthreads();
  if (tid < 64) {
    float r = red[tid] + red[tid + 64] + red[tid + 128] + red[tid + 192];
    out[3 * BS + (size_t)t * V + v] = r * (1.0f / 128.0f);
  }
}

extern "C" void kernel_launch(void* const* d_in, const int* in_sizes, int n_in,
                              void* d_out, int out_size, void* d_ws, size_t ws_size,
                              hipStream_t stream) {
  (void)in_sizes; (void)n_in; (void)out_size;
  const float* emb    = (const float*)d_in[0];
  const float* w_ih   = (const float*)d_in[1];
  const float* w_hh   = (const float*)d_in[2];
  const float* b_ih   = (const float*)d_in[3];
  const float* b_hh   = (const float*)d_in[4];
  const float* w_dist = (const float*)d_in[5];
  const float* b_dist = (const float*)d_in[6];
  float* out = (float*)d_out;

  float* ws = (float*)d_ws;
  float* h      = ws;                      // B*H
  float* x      = h + B * H;               // B*E
  float* gx     = x + B * E;               // B*3H
  float* gh     = gx + B * 3 * H;          // B*3H
  float* logits = gh + B * 3 * H;          // B*V
  float* pm     = logits + (size_t)B * V;  // B*PSTRIDE
  float* ps     = pm + B * PSTRIDE;
  float* pbest  = ps + B * PSTRIDE;
  int*   pidx   = (int*)(pbest + B * PSTRIDE);
  float* rowm   = (float*)(pidx + B * PSTRIDE);
  float* rowz   = rowm + B;
  int*   samp   = (int*)(rowz + B);
  ushort* hhi   = (ushort*)(samp + B);                 // B*H
  ushort* hlo   = hhi + (size_t)B * H;                 // B*H
  // small gru arrays BEFORE the big dist split region, so need_gru <= need_dist
  ushort* xhi   = hlo + (size_t)B * H;                 // B*E
  ushort* xlo   = xhi + (size_t)B * E;                 // B*E
  // dist split region
  ushort* whi   = xlo + (size_t)B * E;                 // V*H
  ushort* wlo   = whi + (size_t)V * H;                 // V*H

  size_t need_gru  = (size_t)((char*)whi - (char*)d_ws);
  size_t need_dist = (size_t)((char*)(wlo + (size_t)V * H) - (char*)d_ws);
  const bool use_gru_mfma  = ws_size >= need_gru;
  const bool use_dist_mfma = ws_size >= need_dist;

  init_k<<<512, 256, 0, stream>>>(emb, h, x, hhi, hlo, xhi, xlo);
  if (use_dist_mfma)
    wsplit_k<<<(V * H / 4 + 255) / 256, 256, 0, stream>>>(w_dist, whi, wlo, V * H / 4);

  const uint32_t base0 = 0u, base1 = 42u;   // jax.random.key(42)
  for (int t = 0; t < S; ++t) {
    uint32_t f0 = 0u, f1 = (uint32_t)t;
    tf2x32(base0, base1, f0, f1);                            // k_t = fold_in(base, t)
    uint32_t k1a = 0u, k1b = 0u; tf2x32(f0, f1, k1a, k1b);   // k1 = enc(0,0)
    uint32_t k2a = 0u, k2b = 1u; tf2x32(f0, f1, k2a, k2b);   // k2 = enc(0,1)

    if (use_gru_mfma)
      gemm_gru_mfma<<<192, 256, 0, stream>>>(xhi, xlo, hhi, hlo, w_ih, w_hh,
                                             b_ih, b_hh, gx, gh);
    else
      gemm_gru_k<<<192, 256, 0, stream>>>(x, h, w_ih, w_hh, b_ih, b_hh, gx, gh);
    gru_gates_k<<<512, 256, 0, stream>>>(gx, gh, h, hhi, hlo);
    int nchunk;
    if (use_dist_mfma) {
      gemm_dist_mfma<<<250, 512, 0, stream>>>(hhi, hlo, whi, wlo, b_dist, logits,
                                              pm, ps, pbest, pidx, k1a, k1b, k2a, k2b);
      nchunk = 250;
    } else {
      gemm_dist_k<<<500, 256, 0, stream>>>(h, w_dist, b_dist, logits);
      sample_partial_k<<<1024, 256, 0, stream>>>(logits, pm, ps, pbest, pidx,
                                                 k1a, k1b, k2a, k2b);
      nchunk = NCHUNK;
    }
    sample_final_gather_k<<<128, 128, 0, stream>>>(logits, pm, ps, pbest, pidx,
                                                   rowm, rowz, samp, emb, x, xhi, xlo,
                                                   out, t, k1a, k1b, nchunk);
    probs_k<<<500, 256, 0, stream>>>(logits, rowm, rowz, out, t);
  }
}

// Round 5
// 6268.664 us; speedup vs baseline: 1.0882x; 1.0882x over previous
//
#include <hip/hip_runtime.h>
#include <cstdint>
#include <cmath>

#define V 32000
#define E 512
#define H 1024
#define B 128
#define S 64
#define NCHUNK 8
#define CHUNK 4000       // V / NCHUNK (fallback sampling path)
#define PSTRIDE 250      // partial-array stride: max chunks (mfma fused path: 250)
#define BS (B*S)
#define NEG_HUGE (-3.0e38f)

typedef __attribute__((ext_vector_type(8))) short short8;
typedef __attribute__((ext_vector_type(4))) float f32x4;

// ---------------- threefry2x32 (JAX-exact, 20 rounds) ----------------
#define TFR(x0, x1, r) { x0 += x1; x1 = ((x1) << (r)) | ((x1) >> (32 - (r))); x1 ^= x0; }

__host__ __device__ inline void tf2x32(uint32_t k0, uint32_t k1, uint32_t &x0, uint32_t &x1) {
  uint32_t ks2 = k0 ^ k1 ^ 0x1BD11BDAu;
  x0 += k0; x1 += k1;
  TFR(x0,x1,13) TFR(x0,x1,15) TFR(x0,x1,26) TFR(x0,x1,6)
  x0 += k1;  x1 += ks2 + 1u;
  TFR(x0,x1,17) TFR(x0,x1,29) TFR(x0,x1,16) TFR(x0,x1,24)
  x0 += ks2; x1 += k0 + 2u;
  TFR(x0,x1,13) TFR(x0,x1,15) TFR(x0,x1,26) TFR(x0,x1,6)
  x0 += k0;  x1 += k1 + 3u;
  TFR(x0,x1,17) TFR(x0,x1,29) TFR(x0,x1,16) TFR(x0,x1,24)
  x0 += k1;  x1 += ks2 + 4u;
  TFR(x0,x1,13) TFR(x0,x1,15) TFR(x0,x1,26) TFR(x0,x1,6)
  x0 += ks2; x1 += k0 + 5u;
}

// partitionable threefry 32-bit bits: xor of both output words of enc(hi=0, lo=i)
__device__ __forceinline__ uint32_t tf_bits32(uint32_t ka, uint32_t kb, uint32_t idx) {
  uint32_t x0 = 0u, x1 = idx;
  tf2x32(ka, kb, x0, x1);
  return x0 ^ x1;
}

__device__ __forceinline__ float bits_to_unif(uint32_t b) {
  return __uint_as_float((b >> 9) | 0x3f800000u) - 1.0f;
}

__device__ __forceinline__ float sigmoidf_(float x) { return 1.0f / (1.0f + expf(-x)); }

// bf16 round-to-nearest-even helpers
__device__ __forceinline__ ushort f2bf(float f) {
  uint32_t u = __float_as_uint(f);
  uint32_t r = u + 0x7FFFu + ((u >> 16) & 1u);
  return (ushort)(r >> 16);
}
__device__ __forceinline__ float bf2f(ushort h) { return __uint_as_float(((uint32_t)h) << 16); }

// async global->LDS, 16 B per lane. LDS dest = wave-uniform base + lane*16.
__device__ __forceinline__ void gload16(const ushort* g, ushort* l) {
  __builtin_amdgcn_global_load_lds((const __attribute__((address_space(1))) void*)g,
                                   (__attribute__((address_space(3))) void*)l, 16, 0, 0);
}

// ---------------- f32 GEMM tile (fallback paths only) ----------------
template<int BM, int BN, int BK, int TM, int TN>
__device__ void gemm_tile(const float* __restrict__ A, const float* __restrict__ Wt,
                          const float* __restrict__ bias, float* __restrict__ C,
                          int N, int K, int mblk, int nblk)
{
  constexpr int WP = BN + 4;
  __shared__ __align__(16) float As[BK][BM];
  __shared__ __align__(16) float Ws[BK][WP];
  const int tid = threadIdx.x;
  constexpr int TX = BN / TN;
  constexpr int TY = BM / TM;
  static_assert(TX * TY == 256, "bad tiling");
  const int tx = tid % TX, ty = tid / TX;
  const int n0 = tx * TN, m0 = ty * TM;

  float acc[TM][TN];
#pragma unroll
  for (int i = 0; i < TM; ++i)
#pragma unroll
    for (int j = 0; j < TN; ++j) acc[i][j] = 0.0f;

  constexpr int NA = (BM * BK / 4) / 256;
  constexpr int NW = (BN * BK / 4) / 256;
  static_assert(NA >= 1 && NW >= 1, "tile too small");

  for (int k0 = 0; k0 < K; k0 += BK) {
    __syncthreads();
#pragma unroll
    for (int q = 0; q < NA; ++q) {
      int idx = q * 256 + tid;
      int m = idx / (BK / 4), c = idx % (BK / 4);
      float4 v = *(const float4*)&A[(size_t)(mblk + m) * K + k0 + 4 * c];
      As[4*c+0][m] = v.x; As[4*c+1][m] = v.y; As[4*c+2][m] = v.z; As[4*c+3][m] = v.w;
    }
#pragma unroll
    for (int q = 0; q < NW; ++q) {
      int idx = q * 256 + tid;
      int n = idx / (BK / 4), c = idx % (BK / 4);
      float4 v = *(const float4*)&Wt[(size_t)(nblk + n) * K + k0 + 4 * c];
      Ws[4*c+0][n] = v.x; Ws[4*c+1][n] = v.y; Ws[4*c+2][n] = v.z; Ws[4*c+3][n] = v.w;
    }
    __syncthreads();
#pragma unroll
    for (int k = 0; k < BK; ++k) {
      float a[TM], w[TN];
#pragma unroll
      for (int i = 0; i < TM; ++i) a[i] = As[k][m0 + i];
#pragma unroll
      for (int j = 0; j < TN; ++j) w[j] = Ws[k][n0 + j];
#pragma unroll
      for (int i = 0; i < TM; ++i)
#pragma unroll
        for (int j = 0; j < TN; ++j) acc[i][j] += a[i] * w[j];
    }
  }
#pragma unroll
  for (int i = 0; i < TM; ++i)
#pragma unroll
    for (int j = 0; j < TN; ++j)
      C[(size_t)(mblk + m0 + i) * N + nblk + n0 + j] = acc[i][j] + bias[nblk + n0 + j];
}

// fallback dist GEMM (f32)
__global__ __launch_bounds__(256) void gemm_dist_k(const float* __restrict__ h,
    const float* __restrict__ w_dist, const float* __restrict__ b_dist,
    float* __restrict__ logits)
{
  gemm_tile<128, 64, 16, 8, 4>(h, w_dist, b_dist, logits, V, H, 0, blockIdx.x * 64);
}

// fallback GRU gemms (f32)
__global__ __launch_bounds__(256) void gemm_gru_k(const float* __restrict__ x,
    const float* __restrict__ h, const float* __restrict__ w_ih, const float* __restrict__ w_hh,
    const float* __restrict__ b_ih, const float* __restrict__ b_hh,
    float* __restrict__ gx, float* __restrict__ gh)
{
  int b = blockIdx.x;
  if (b < 96) {
    int rb = b & 1, cb = b >> 1;
    gemm_tile<64, 64, 16, 4, 4>(x, w_ih, b_ih, gx, 3 * H, E, rb * 64, cb * 64);
  } else {
    b -= 96;
    int rb = b & 1, cb = b >> 1;
    gemm_tile<64, 64, 16, 4, 4>(h, w_hh, b_hh, gh, 3 * H, H, rb * 64, cb * 64);
  }
}

// split f32 -> bf16 hi/lo (once per call); n4 = count of float4 groups
__global__ __launch_bounds__(256) void wsplit_k(const float* __restrict__ w,
    ushort* __restrict__ whi, ushort* __restrict__ wlo, int n4)
{
  int idx = blockIdx.x * 256 + threadIdx.x;
  if (idx >= n4) return;
  size_t i = (size_t)idx * 4;
  float4 v = *(const float4*)&w[i];
  ushort h0 = f2bf(v.x), h1 = f2bf(v.y), h2 = f2bf(v.z), h3 = f2bf(v.w);
  ushort l0 = f2bf(v.x - bf2f(h0)), l1 = f2bf(v.y - bf2f(h1));
  ushort l2 = f2bf(v.z - bf2f(h2)), l3 = f2bf(v.w - bf2f(h3));
  ushort4 hv = {h0, h1, h2, h3}, lv = {l0, l1, l2, l3};
  *(ushort4*)&whi[i] = hv;
  *(ushort4*)&wlo[i] = lv;
}

// GRU gates, h updated in place; also emits bf16 hi/lo split of h
__global__ __launch_bounds__(256) void gru_gates_k(const float* __restrict__ gx,
    const float* __restrict__ gh, float* __restrict__ h,
    ushort* __restrict__ hhi, ushort* __restrict__ hlo)
{
  int idx = blockIdx.x * 256 + threadIdx.x;   // B*H = 131072
  int b = idx >> 10, j = idx & 1023;
  const float* gxb = gx + (size_t)b * 3 * H;
  const float* ghb = gh + (size_t)b * 3 * H;
  float r = sigmoidf_(gxb[j] + ghb[j]);
  float z = sigmoidf_(gxb[H + j] + ghb[H + j]);
  float n = tanhf(gxb[2 * H + j] + r * ghb[2 * H + j]);
  float hn = (1.0f - z) * n + z * h[idx];
  h[idx] = hn;
  ushort hi = f2bf(hn);
  hhi[idx] = hi;
  hlo[idx] = f2bf(hn - bf2f(hi));
}

// ---------------- MFMA bf16x3 dist GEMM with FUSED sampling partials ----------------
// Double-buffered global_load_lds staging with T4 COUNTED vmcnt: issue next stage,
// wait vmcnt(4) (only the loads issued a full K-step ago), barrier, compute, barrier.
// Never drains to 0 in the main loop; last iter uses vmcnt(0). Quad-XOR swizzle on
// both sides (pre-swizzled global source + swizzled ds_read) as verified in R3.
__global__ __launch_bounds__(512) void gemm_dist_mfma(const ushort* __restrict__ hhi,
    const ushort* __restrict__ hlo, const ushort* __restrict__ whi,
    const ushort* __restrict__ wlo, const float* __restrict__ b_dist,
    float* __restrict__ logits,
    float* __restrict__ pm, float* __restrict__ ps,
    float* __restrict__ pbest, int* __restrict__ pidx,
    uint32_t k1a, uint32_t k1b, uint32_t k2a, uint32_t k2b)
{
  __shared__ ushort Ah[2][128 * 32], Al[2][128 * 32], Wh[2][128 * 32], Wl[2][128 * 32];
  __shared__ float rm[2 * 128], rs[2 * 128], rb_[2 * 128];
  __shared__ int   ri[2 * 128];
  __shared__ uint32_t sdraw[128];
  const int tid = threadIdx.x;
  const int wave = tid >> 6, lane = tid & 63;
  const int wm = (wave & 3) * 32;
  const int wn = (wave >> 2) * 64;
  const int nblk = blockIdx.x * 128;
  const int l15 = lane & 15;
  const int q = lane >> 4;

  // per-row epsilon-draw flags (read only in epilogue, after many barriers)
  if (tid < 128)
    sdraw[tid] = (bits_to_unif(tf_bits32(k1a, k1b, (uint32_t)tid)) <= 0.05f) ? 1u : 0u;

  const int sr = tid >> 2;
  const int gq8 = ((tid & 3) ^ ((sr >> 1) & 3)) * 8;
  const size_t arow = (size_t)sr * 1024 + gq8;
  const size_t wrow = (size_t)(nblk + sr) * 1024 + gq8;
  const int wbase = wave * 512;

#define DIST_STAGE(bf, kk) {                                   \
    gload16(&hhi[arow + (kk)], &Ah[bf][wbase]);                \
    gload16(&hlo[arow + (kk)], &Al[bf][wbase]);                \
    gload16(&whi[wrow + (kk)], &Wh[bf][wbase]);                \
    gload16(&wlo[wrow + (kk)], &Wl[bf][wbase]);                \
  }

  f32x4 acc[2][4] = {};

  DIST_STAGE(0, 0);            // 4 loads in flight; waited inside iter 0

  int buf = 0;
  for (int k0 = 0; k0 < 1024; k0 += 32, buf ^= 1) {
    const bool more = (k0 + 32 < 1024);
    if (more) {
      DIST_STAGE(buf ^ 1, k0 + 32);                       // up to 8 in flight
      asm volatile("s_waitcnt vmcnt(4)" ::: "memory");     // oldest 4 (this buf) landed
    } else {
      asm volatile("s_waitcnt vmcnt(0)" ::: "memory");     // final buf landed
    }
    __builtin_amdgcn_sched_barrier(0);
    __builtin_amdgcn_s_barrier();                          // all waves' buf loads landed
    __builtin_amdgcn_sched_barrier(0);

    short8 ah[2], al[2], wh[4], wl[4];
#pragma unroll
    for (int mt = 0; mt < 2; ++mt) {
      int row = wm + mt * 16 + l15;
      int off = row * 32 + ((q ^ ((row >> 1) & 3)) * 8);
      ah[mt] = *(const short8*)&Ah[buf][off];
      al[mt] = *(const short8*)&Al[buf][off];
    }
#pragma unroll
    for (int nt = 0; nt < 4; ++nt) {
      int row = wn + nt * 16 + l15;
      int off = row * 32 + ((q ^ ((row >> 1) & 3)) * 8);
      wh[nt] = *(const short8*)&Wh[buf][off];
      wl[nt] = *(const short8*)&Wl[buf][off];
    }
#pragma unroll
    for (int mt = 0; mt < 2; ++mt)
#pragma unroll
      for (int nt = 0; nt < 4; ++nt) {
        acc[mt][nt] = __builtin_amdgcn_mfma_f32_16x16x32_bf16(ah[mt], wh[nt], acc[mt][nt], 0, 0, 0);
        acc[mt][nt] = __builtin_amdgcn_mfma_f32_16x16x32_bf16(al[mt], wh[nt], acc[mt][nt], 0, 0, 0);
        acc[mt][nt] = __builtin_amdgcn_mfma_f32_16x16x32_bf16(ah[mt], wl[nt], acc[mt][nt], 0, 0, 0);
      }

    __builtin_amdgcn_s_barrier();                          // reads of buf done -> next
  }                                                        // iter may DMA into it
#undef DIST_STAGE

  // -------- epilogue: store logits + fused sampling partials --------
  float bv[4];
#pragma unroll
  for (int nt = 0; nt < 4; ++nt) bv[nt] = b_dist[nblk + wn + nt * 16 + l15];

  const float LOGU = -logf((float)V);
#pragma unroll
  for (int mt = 0; mt < 2; ++mt) {
#pragma unroll
    for (int reg = 0; reg < 4; ++reg) {
      const int r = wm + mt * 16 + q * 4 + reg;     // batch row
      const bool draw = sdraw[r] != 0u;
      float m0 = NEG_HUGE, s0 = 0.0f, best = NEG_HUGE;
      int bi = 2147483647;
#pragma unroll
      for (int nt = 0; nt < 4; ++nt) {
        const int col = nblk + wn + nt * 16 + l15;
        float a = acc[mt][nt][reg] + bv[nt];
        logits[(size_t)r * V + col] = a;
        if (a > m0) { s0 = s0 * expf(m0 - a) + 1.0f; m0 = a; } else { s0 += expf(a - m0); }
        uint32_t bits = tf_bits32(k2a, k2b, (uint32_t)(r * V + col));
        float g = -logf(-logf(bits_to_unif(bits)));
        float key = draw ? (LOGU + g) : (a + g);
        if (key > best) { best = key; bi = col; }
      }
      // reduce across the 16 lanes of this quarter-wave (same row r)
#pragma unroll
      for (int off = 1; off < 16; off <<= 1) {
        float mo = __shfl_xor(m0, off);
        float so = __shfl_xor(s0, off);
        float M = fmaxf(m0, mo);
        s0 = s0 * expf(m0 - M) + so * expf(mo - M);
        m0 = M;
        float bo = __shfl_xor(best, off);
        int io = __shfl_xor(bi, off);
        if (bo > best || (bo == best && io < bi)) { best = bo; bi = io; }
      }
      if (l15 == 0) {
        const int slot = (wave >> 2) * 128 + r;     // [wn-group][row]
        rm[slot] = m0; rs[slot] = s0; rb_[slot] = best; ri[slot] = bi;
      }
    }
  }
  __syncthreads();
  // combine the two wn-groups per row, write chunk partials
  if (tid < 128) {
    float ma = rm[tid], sa = rs[tid], mb = rm[128 + tid], sb = rs[128 + tid];
    float M = fmaxf(ma, mb);
    float s = sa * expf(ma - M) + sb * expf(mb - M);
    pm[tid * PSTRIDE + blockIdx.x] = M;
    ps[tid * PSTRIDE + blockIdx.x] = s;
    float va = rb_[tid], vb = rb_[128 + tid];
    int ia = ri[tid], ib = ri[128 + tid];
    if (vb > va || (vb == va && ib < ia)) { va = vb; ia = ib; }
    pbest[tid * PSTRIDE + blockIdx.x] = va;
    pidx[tid * PSTRIDE + blockIdx.x] = ia;
  }
}

// ---------------- MFMA bf16x3 64x64-tile GEMM (GRU) ----------------
// 256 threads = 4 waves, wave tile 32x32 (2x2 of 16x16), BK=32.
// Same T4 counted-vmcnt 2-phase structure as the dist GEMM.
__device__ void gemm64_bf16x3(const ushort* __restrict__ Ahi_g, const ushort* __restrict__ Alo_g,
    const ushort* __restrict__ Whi_g, const ushort* __restrict__ Wlo_g,
    const float* __restrict__ bias, float* __restrict__ C,
    int N, int K, int mblk, int nblk)
{
  __shared__ ushort Ah[2][64 * 32], Al[2][64 * 32], Wh[2][64 * 32], Wl[2][64 * 32];
  const int tid = threadIdx.x;
  const int wave = tid >> 6, lane = tid & 63;
  const int wm = (wave & 1) * 32, wn = (wave >> 1) * 32;
  const int l15 = lane & 15, q = lane >> 4;

  const int sr = tid >> 2;
  const int gq8 = ((tid & 3) ^ ((sr >> 1) & 3)) * 8;
  const size_t arow = (size_t)(mblk + sr) * K + gq8;
  const size_t wrow = (size_t)(nblk + sr) * K + gq8;
  const int wbase = wave * 512;

#define GRU_STAGE(bf, kk) {                                    \
    gload16(&Ahi_g[arow + (kk)], &Ah[bf][wbase]);              \
    gload16(&Alo_g[arow + (kk)], &Al[bf][wbase]);              \
    gload16(&Whi_g[wrow + (kk)], &Wh[bf][wbase]);              \
    gload16(&Wlo_g[wrow + (kk)], &Wl[bf][wbase]);              \
  }

  f32x4 acc[2][2] = {};

  GRU_STAGE(0, 0);

  int buf = 0;
  for (int k0 = 0; k0 < K; k0 += 32, buf ^= 1) {
    const bool more = (k0 + 32 < K);
    if (more) {
      GRU_STAGE(buf ^ 1, k0 + 32);
      asm volatile("s_waitcnt vmcnt(4)" ::: "memory");
    } else {
      asm volatile("s_waitcnt vmcnt(0)" ::: "memory");
    }
    __builtin_amdgcn_sched_barrier(0);
    __builtin_amdgcn_s_barrier();
    __builtin_amdgcn_sched_barrier(0);

    short8 ah[2], al[2], wh[2], wl[2];
#pragma unroll
    for (int mt = 0; mt < 2; ++mt) {
      int row = wm + mt * 16 + l15;
      int off = row * 32 + ((q ^ ((row >> 1) & 3)) * 8);
      ah[mt] = *(const short8*)&Ah[buf][off];
      al[mt] = *(const short8*)&Al[buf][off];
    }
#pragma unroll
    for (int nt = 0; nt < 2; ++nt) {
      int row = wn + nt * 16 + l15;
      int off = row * 32 + ((q ^ ((row >> 1) & 3)) * 8);
      wh[nt] = *(const short8*)&Wh[buf][off];
      wl[nt] = *(const short8*)&Wl[buf][off];
    }
#pragma unroll
    for (int mt = 0; mt < 2; ++mt)
#pragma unroll
      for (int nt = 0; nt < 2; ++nt) {
        acc[mt][nt] = __builtin_amdgcn_mfma_f32_16x16x32_bf16(ah[mt], wh[nt], acc[mt][nt], 0, 0, 0);
        acc[mt][nt] = __builtin_amdgcn_mfma_f32_16x16x32_bf16(al[mt], wh[nt], acc[mt][nt], 0, 0, 0);
        acc[mt][nt] = __builtin_amdgcn_mfma_f32_16x16x32_bf16(ah[mt], wl[nt], acc[mt][nt], 0, 0, 0);
      }

    __builtin_amdgcn_s_barrier();
  }
#undef GRU_STAGE

#pragma unroll
  for (int nt = 0; nt < 2; ++nt) {
    int col = nblk + wn + nt * 16 + l15;
    float bv = bias[col];
#pragma unroll
    for (int mt = 0; mt < 2; ++mt) {
      int rbase = mblk + wm + mt * 16 + (lane >> 4) * 4;
#pragma unroll
      for (int reg = 0; reg < 4; ++reg)
        C[(size_t)(rbase + reg) * N + col] = acc[mt][nt][reg] + bv;
    }
  }
}

// one dispatch for gx (blocks 0..95) + gh (blocks 96..191).
__global__ __launch_bounds__(256) void gemm_gru_mfma(
    const ushort* __restrict__ xhi, const ushort* __restrict__ xlo,
    const ushort* __restrict__ hhi, const ushort* __restrict__ hlo,
    const ushort* __restrict__ wihhi, const ushort* __restrict__ wihlo,
    const ushort* __restrict__ whhhi, const ushort* __restrict__ whhlo,
    const float* __restrict__ b_ih, const float* __restrict__ b_hh,
    float* __restrict__ gx, float* __restrict__ gh)
{
  int b = blockIdx.x;
  if (b < 96) {
    int mblk = (b & 1) * 64, nblk = (b >> 1) * 64;
    gemm64_bf16x3(xhi, xlo, wihhi, wihlo, b_ih, gx, 3 * H, E, mblk, nblk);
  } else {
    b -= 96;
    int mblk = (b & 1) * 64, nblk = (b >> 1) * 64;
    gemm64_bf16x3(hhi, hlo, whhhi, whhlo, b_hh, gh, 3 * H, H, mblk, nblk);
  }
}

// init: h = 0 (and its bf16 splits), x = broadcast emb[0] (and its bf16 splits)
__global__ __launch_bounds__(256) void init_k(const float* __restrict__ emb,
    float* __restrict__ h, float* __restrict__ x,
    ushort* __restrict__ hhi, ushort* __restrict__ hlo,
    ushort* __restrict__ xhi, ushort* __restrict__ xlo)
{
  int i = blockIdx.x * 256 + threadIdx.x;   // grid covers B*H
  if (i < B * H) { h[i] = 0.0f; hhi[i] = 0; hlo[i] = 0; }
  if (i < B * E) {
    float v = emb[i & (E - 1)];
    x[i] = v;
    ushort hi = f2bf(v);
    xhi[i] = hi;
    xlo[i] = f2bf(v - bf2f(hi));
  }
}

// fallback pass (f32 dist path only)
__global__ __launch_bounds__(256) void sample_partial_k(const float* __restrict__ logits,
    float* __restrict__ pm, float* __restrict__ ps,
    float* __restrict__ pbest, int* __restrict__ pidx,
    uint32_t k1a, uint32_t k1b, uint32_t k2a, uint32_t k2b)
{
  const int b = blockIdx.x & 127, chunk = blockIdx.x >> 7;
  const int tid = threadIdx.x;
  const bool draw = bits_to_unif(tf_bits32(k1a, k1b, (uint32_t)b)) <= 0.05f;
  const float LOGU = -logf((float)V);
  const int vbeg = chunk * CHUNK, vend = vbeg + CHUNK;
  float m0 = -INFINITY, s0 = 0.0f, best = -INFINITY;
  int bi = 2147483647;
  for (int v = vbeg + tid; v < vend; v += 256) {
    float a = logits[(size_t)b * V + v];
    if (a > m0) { s0 = s0 * expf(m0 - a) + 1.0f; m0 = a; } else { s0 += expf(a - m0); }
    uint32_t bits = tf_bits32(k2a, k2b, (uint32_t)(b * V + v));
    float g = -logf(-logf(bits_to_unif(bits)));
    float key = draw ? (LOGU + g) : (a + g);
    if (key > best) { best = key; bi = v; }
  }
  __shared__ float shm[256], shs[256], sv[256];
  __shared__ int si[256];
  shm[tid] = m0; shs[tid] = s0; sv[tid] = best; si[tid] = bi;
  __syncthreads();
  for (int off = 128; off > 0; off >>= 1) {
    if (tid < off) {
      float ma = shm[tid], sa = shs[tid];
      float mb = shm[tid + off], sb = shs[tid + off];
      float M = fmaxf(ma, mb);
      shm[tid] = M;
      shs[tid] = sa * expf(ma - M) + sb * expf(mb - M);
      float va = sv[tid], vb = sv[tid + off];
      int ia = si[tid], ib = si[tid + off];
      if (vb > va || (vb == va && ib < ia)) { sv[tid] = vb; si[tid] = ib; }
    }
    __syncthreads();
  }
  if (tid == 0) {
    pm[b * PSTRIDE + chunk] = shm[0]; ps[b * PSTRIDE + chunk] = shs[0];
    pbest[b * PSTRIDE + chunk] = sv[0]; pidx[b * PSTRIDE + chunk] = si[0];
  }
}

// fused final: block b = row b, 128 threads
__global__ __launch_bounds__(128) void sample_final_gather_k(const float* __restrict__ logits,
    const float* __restrict__ pm, const float* __restrict__ ps,
    const float* __restrict__ pbest, const int* __restrict__ pidx,
    float* __restrict__ rowm, float* __restrict__ rowz, int* __restrict__ samp,
    const float* __restrict__ emb, float* __restrict__ x,
    ushort* __restrict__ xhi, ushort* __restrict__ xlo,
    float* __restrict__ out, int t, uint32_t k1a, uint32_t k1b, int nchunk)
{
  __shared__ float shm[128], shs[128], shb[128];
  __shared__ int shi[128];
  __shared__ int sh_idx;
  const int b = blockIdx.x, tid = threadIdx.x;
  float m0 = NEG_HUGE, s0 = 0.0f, best = NEG_HUGE;
  int bi = 2147483647;
  for (int c = tid; c < nchunk; c += 128) {
    float ma = pm[b * PSTRIDE + c], sa = ps[b * PSTRIDE + c];
    float M = fmaxf(m0, ma);
    s0 = s0 * expf(m0 - M) + sa * expf(ma - M);
    m0 = M;
    float v = pbest[b * PSTRIDE + c];
    int ix = pidx[b * PSTRIDE + c];
    if (v > best || (v == best && ix < bi)) { best = v; bi = ix; }
  }
  shm[tid] = m0; shs[tid] = s0; shb[tid] = best; shi[tid] = bi;
  __syncthreads();
  for (int off = 64; off > 0; off >>= 1) {
    if (tid < off) {
      float ma = shm[tid], sa = shs[tid];
      float mb = shm[tid + off], sb = shs[tid + off];
      float M = fmaxf(ma, mb);
      shm[tid] = M;
      shs[tid] = sa * expf(ma - M) + sb * expf(mb - M);
      float va = shb[tid], vb = shb[tid + off];
      int ia = shi[tid], ib = shi[tid + off];
      if (vb > va || (vb == va && ib < ia)) { shb[tid] = vb; shi[tid] = ib; }
    }
    __syncthreads();
  }
  if (tid == 0) {
    float mrow = shm[0];
    float z0 = logf(shs[0]);
    int idx = shi[0];
    rowm[b] = mrow; rowz[b] = z0;
    float lp = (logits[(size_t)b * V + idx] - mrow) - z0;
    bool draw = bits_to_unif(tf_bits32(k1a, k1b, (uint32_t)b)) <= 0.05f;
    float corr = 1.0f;
    if (draw) {
      const float LOGU = -logf((float)V);
      float onp = fminf(fmaxf(expf(lp), 1e-8f), 1.0f);
      float offp = fminf(fmaxf(expf(LOGU), 1e-8f), 1.0f);
      corr = onp / offp;
    }
    out[b * S + t] = (float)idx;
    out[BS + b * S + t] = corr;
    out[2 * BS + b * S + t] = lp;
    samp[b] = idx;
    sh_idx = idx;
  }
  __syncthreads();
  const int row = sh_idx;
  float4 v = *(const float4*)&emb[(size_t)row * E + tid * 4];
  *(float4*)&x[(size_t)b * E + tid * 4] = v;
  ushort h0 = f2bf(v.x), h1 = f2bf(v.y), h2 = f2bf(v.z), h3 = f2bf(v.w);
  ushort l0 = f2bf(v.x - bf2f(h0)), l1 = f2bf(v.y - bf2f(h1));
  ushort l2 = f2bf(v.z - bf2f(h2)), l3 = f2bf(v.w - bf2f(h3));
  ushort4 hv = {h0, h1, h2, h3}, lv = {l0, l1, l2, l3};
  *(ushort4*)&xhi[(size_t)b * E + tid * 4] = hv;
  *(ushort4*)&xlo[(size_t)b * E + tid * 4] = lv;
}

// probs[t, v] = mean_b exp(dist[b, v])
__global__ __launch_bounds__(256) void probs_k(const float* __restrict__ logits,
    const float* __restrict__ rowm, const float* __restrict__ rowz,
    float* __restrict__ out, int t)
{
  __shared__ float sm[B], sz[B];
  __shared__ float red[256];
  const int tid = threadIdx.x;
  if (tid < B) { sm[tid] = rowm[tid]; sz[tid] = rowz[tid]; }
  __syncthreads();
  const int v = blockIdx.x * 64 + (tid & 63);
  const int bh = tid >> 6;
  float acc = 0.0f;
#pragma unroll 4
  for (int i = 0; i < 32; ++i) {
    int b = bh * 32 + i;
    acc += expf((logits[(size_t)b * V + v] - sm[b]) - sz[b]);
  }
  red[tid] = acc;
  __syncthreads();
  if (tid < 64) {
    float r = red[tid] + red[tid + 64] + red[tid + 128] + red[tid + 192];
    out[3 * BS + (size_t)t * V + v] = r * (1.0f / 128.0f);
  }
}

extern "C" void kernel_launch(void* const* d_in, const int* in_sizes, int n_in,
                              void* d_out, int out_size, void* d_ws, size_t ws_size,
                              hipStream_t stream) {
  (void)in_sizes; (void)n_in; (void)out_size;
  const float* emb    = (const float*)d_in[0];
  const float* w_ih   = (const float*)d_in[1];
  const float* w_hh   = (const float*)d_in[2];
  const float* b_ih   = (const float*)d_in[3];
  const float* b_hh   = (const float*)d_in[4];
  const float* w_dist = (const float*)d_in[5];
  const float* b_dist = (const float*)d_in[6];
  float* out = (float*)d_out;

  float* ws = (float*)d_ws;
  float* h      = ws;                      // B*H
  float* x      = h + B * H;               // B*E
  float* gx     = x + B * E;               // B*3H
  float* gh     = gx + B * 3 * H;          // B*3H
  float* logits = gh + B * 3 * H;          // B*V
  float* pm     = logits + (size_t)B * V;  // B*PSTRIDE
  float* ps     = pm + B * PSTRIDE;
  float* pbest  = ps + B * PSTRIDE;
  int*   pidx   = (int*)(pbest + B * PSTRIDE);
  float* rowm   = (float*)(pidx + B * PSTRIDE);
  float* rowz   = rowm + B;
  int*   samp   = (int*)(rowz + B);
  ushort* hhi   = (ushort*)(samp + B);                 // B*H
  ushort* hlo   = hhi + (size_t)B * H;                 // B*H
  // dist split region
  ushort* whi   = hlo + (size_t)B * H;                 // V*H
  ushort* wlo   = whi + (size_t)V * H;                 // V*H
  // gru split region
  ushort* xhi   = wlo + (size_t)V * H;                 // B*E
  ushort* xlo   = xhi + (size_t)B * E;                 // B*E
  ushort* wihhi = xlo + (size_t)B * E;                 // 3H*E
  ushort* wihlo = wihhi + (size_t)3 * H * E;           // 3H*E
  ushort* whhhi = wihlo + (size_t)3 * H * E;           // 3H*H
  ushort* whhlo = whhhi + (size_t)3 * H * H;           // 3H*H

  size_t need_dist = (size_t)((char*)xhi - (char*)d_ws);
  size_t need_gru  = (size_t)((char*)(whhlo + (size_t)3 * H * H) - (char*)d_ws);
  const bool use_dist_mfma = ws_size >= need_dist;
  const bool use_gru_mfma  = ws_size >= need_gru;

  init_k<<<512, 256, 0, stream>>>(emb, h, x, hhi, hlo, xhi, xlo);
  if (use_dist_mfma)
    wsplit_k<<<(V * H / 4 + 255) / 256, 256, 0, stream>>>(w_dist, whi, wlo, V * H / 4);
  if (use_gru_mfma) {
    wsplit_k<<<(3 * H * E / 4 + 255) / 256, 256, 0, stream>>>(w_ih, wihhi, wihlo, 3 * H * E / 4);
    wsplit_k<<<(3 * H * H / 4 + 255) / 256, 256, 0, stream>>>(w_hh, whhhi, whhlo, 3 * H * H / 4);
  }

  const uint32_t base0 = 0u, base1 = 42u;   // jax.random.key(42)
  for (int t = 0; t < S; ++t) {
    uint32_t f0 = 0u, f1 = (uint32_t)t;
    tf2x32(base0, base1, f0, f1);                            // k_t = fold_in(base, t)
    uint32_t k1a = 0u, k1b = 0u; tf2x32(f0, f1, k1a, k1b);   // k1 = enc(0,0)
    uint32_t k2a = 0u, k2b = 1u; tf2x32(f0, f1, k2a, k2b);   // k2 = enc(0,1)

    if (use_gru_mfma)
      gemm_gru_mfma<<<192, 256, 0, stream>>>(xhi, xlo, hhi, hlo, wihhi, wihlo,
                                             whhhi, whhlo, b_ih, b_hh, gx, gh);
    else
      gemm_gru_k<<<192, 256, 0, stream>>>(x, h, w_ih, w_hh, b_ih, b_hh, gx, gh);
    gru_gates_k<<<512, 256, 0, stream>>>(gx, gh, h, hhi, hlo);
    int nchunk;
    if (use_dist_mfma) {
      gemm_dist_mfma<<<250, 512, 0, stream>>>(hhi, hlo, whi, wlo, b_dist, logits,
                                              pm, ps, pbest, pidx, k1a, k1b, k2a, k2b);
      nchunk = 250;
    } else {
      gemm_dist_k<<<500, 256, 0, stream>>>(h, w_dist, b_dist, logits);
      sample_partial_k<<<1024, 256, 0, stream>>>(logits, pm, ps, pbest, pidx,
                                                 k1a, k1b, k2a, k2b);
      nchunk = NCHUNK;
    }
    sample_final_gather_k<<<128, 128, 0, stream>>>(logits, pm, ps, pbest, pidx,
                                                   rowm, rowz, samp, emb, x, xhi, xlo,
                                                   out, t, k1a, k1b, nchunk);
    probs_k<<<500, 256, 0, stream>>>(logits, rowm, rowz, out, t);
  }
}

// Round 6
// 6054.314 us; speedup vs baseline: 1.1268x; 1.0354x over previous
//
#include <hip/hip_runtime.h>
#include <cstdint>
#include <cmath>

#define V 32000
#define E 512
#define H 1024
#define B 128
#define S 64
#define NCHUNK 8
#define CHUNK 4000       // V / NCHUNK (fallback sampling path)
#define PSTRIDE 250      // partial-array stride: max chunks (mfma fused path: 250)
#define BS (B*S)
#define NEG_HUGE (-3.0e38f)

typedef __attribute__((ext_vector_type(8))) short short8;
typedef __attribute__((ext_vector_type(4))) float f32x4;

// ---------------- threefry2x32 (JAX-exact, 20 rounds) ----------------
#define TFR(x0, x1, r) { x0 += x1; x1 = ((x1) << (r)) | ((x1) >> (32 - (r))); x1 ^= x0; }

__host__ __device__ inline void tf2x32(uint32_t k0, uint32_t k1, uint32_t &x0, uint32_t &x1) {
  uint32_t ks2 = k0 ^ k1 ^ 0x1BD11BDAu;
  x0 += k0; x1 += k1;
  TFR(x0,x1,13) TFR(x0,x1,15) TFR(x0,x1,26) TFR(x0,x1,6)
  x0 += k1;  x1 += ks2 + 1u;
  TFR(x0,x1,17) TFR(x0,x1,29) TFR(x0,x1,16) TFR(x0,x1,24)
  x0 += ks2; x1 += k0 + 2u;
  TFR(x0,x1,13) TFR(x0,x1,15) TFR(x0,x1,26) TFR(x0,x1,6)
  x0 += k0;  x1 += k1 + 3u;
  TFR(x0,x1,17) TFR(x0,x1,29) TFR(x0,x1,16) TFR(x0,x1,24)
  x0 += k1;  x1 += ks2 + 4u;
  TFR(x0,x1,13) TFR(x0,x1,15) TFR(x0,x1,26) TFR(x0,x1,6)
  x0 += ks2; x1 += k0 + 5u;
}

// partitionable threefry 32-bit bits: xor of both output words of enc(hi=0, lo=i)
__device__ __forceinline__ uint32_t tf_bits32(uint32_t ka, uint32_t kb, uint32_t idx) {
  uint32_t x0 = 0u, x1 = idx;
  tf2x32(ka, kb, x0, x1);
  return x0 ^ x1;
}

__device__ __forceinline__ float bits_to_unif(uint32_t b) {
  return __uint_as_float((b >> 9) | 0x3f800000u) - 1.0f;
}

__device__ __forceinline__ float sigmoidf_(float x) { return 1.0f / (1.0f + expf(-x)); }

// bf16 round-to-nearest-even helpers
__device__ __forceinline__ ushort f2bf(float f) {
  uint32_t u = __float_as_uint(f);
  uint32_t r = u + 0x7FFFu + ((u >> 16) & 1u);
  return (ushort)(r >> 16);
}
__device__ __forceinline__ float bf2f(ushort h) { return __uint_as_float(((uint32_t)h) << 16); }

// async global->LDS, 16 B per lane. LDS dest = wave-uniform base + lane*16.
__device__ __forceinline__ void gload16(const ushort* g, ushort* l) {
  __builtin_amdgcn_global_load_lds((const __attribute__((address_space(1))) void*)g,
                                   (__attribute__((address_space(3))) void*)l, 16, 0, 0);
}

// ---------------- f32 GEMM tile (fallback paths only) ----------------
template<int BM, int BN, int BK, int TM, int TN>
__device__ void gemm_tile(const float* __restrict__ A, const float* __restrict__ Wt,
                          const float* __restrict__ bias, float* __restrict__ C,
                          int N, int K, int mblk, int nblk)
{
  constexpr int WP = BN + 4;
  __shared__ __align__(16) float As[BK][BM];
  __shared__ __align__(16) float Ws[BK][WP];
  const int tid = threadIdx.x;
  constexpr int TX = BN / TN;
  constexpr int TY = BM / TM;
  static_assert(TX * TY == 256, "bad tiling");
  const int tx = tid % TX, ty = tid / TX;
  const int n0 = tx * TN, m0 = ty * TM;

  float acc[TM][TN];
#pragma unroll
  for (int i = 0; i < TM; ++i)
#pragma unroll
    for (int j = 0; j < TN; ++j) acc[i][j] = 0.0f;

  constexpr int NA = (BM * BK / 4) / 256;
  constexpr int NW = (BN * BK / 4) / 256;
  static_assert(NA >= 1 && NW >= 1, "tile too small");

  for (int k0 = 0; k0 < K; k0 += BK) {
    __syncthreads();
#pragma unroll
    for (int q = 0; q < NA; ++q) {
      int idx = q * 256 + tid;
      int m = idx / (BK / 4), c = idx % (BK / 4);
      float4 v = *(const float4*)&A[(size_t)(mblk + m) * K + k0 + 4 * c];
      As[4*c+0][m] = v.x; As[4*c+1][m] = v.y; As[4*c+2][m] = v.z; As[4*c+3][m] = v.w;
    }
#pragma unroll
    for (int q = 0; q < NW; ++q) {
      int idx = q * 256 + tid;
      int n = idx / (BK / 4), c = idx % (BK / 4);
      float4 v = *(const float4*)&Wt[(size_t)(nblk + n) * K + k0 + 4 * c];
      Ws[4*c+0][n] = v.x; Ws[4*c+1][n] = v.y; Ws[4*c+2][n] = v.z; Ws[4*c+3][n] = v.w;
    }
    __syncthreads();
#pragma unroll
    for (int k = 0; k < BK; ++k) {
      float a[TM], w[TN];
#pragma unroll
      for (int i = 0; i < TM; ++i) a[i] = As[k][m0 + i];
#pragma unroll
      for (int j = 0; j < TN; ++j) w[j] = Ws[k][n0 + j];
#pragma unroll
      for (int i = 0; i < TM; ++i)
#pragma unroll
        for (int j = 0; j < TN; ++j) acc[i][j] += a[i] * w[j];
    }
  }
#pragma unroll
  for (int i = 0; i < TM; ++i)
#pragma unroll
    for (int j = 0; j < TN; ++j)
      C[(size_t)(mblk + m0 + i) * N + nblk + n0 + j] = acc[i][j] + bias[nblk + n0 + j];
}

// fallback dist GEMM (f32)
__global__ __launch_bounds__(256) void gemm_dist_k(const float* __restrict__ h,
    const float* __restrict__ w_dist, const float* __restrict__ b_dist,
    float* __restrict__ logits)
{
  gemm_tile<128, 64, 16, 8, 4>(h, w_dist, b_dist, logits, V, H, 0, blockIdx.x * 64);
}

// fallback GRU gemms (f32)
__global__ __launch_bounds__(256) void gemm_gru_k(const float* __restrict__ x,
    const float* __restrict__ h, const float* __restrict__ w_ih, const float* __restrict__ w_hh,
    const float* __restrict__ b_ih, const float* __restrict__ b_hh,
    float* __restrict__ gx, float* __restrict__ gh)
{
  int b = blockIdx.x;
  if (b < 96) {
    int rb = b & 1, cb = b >> 1;
    gemm_tile<64, 64, 16, 4, 4>(x, w_ih, b_ih, gx, 3 * H, E, rb * 64, cb * 64);
  } else {
    b -= 96;
    int rb = b & 1, cb = b >> 1;
    gemm_tile<64, 64, 16, 4, 4>(h, w_hh, b_hh, gh, 3 * H, H, rb * 64, cb * 64);
  }
}

// split f32 -> bf16 hi/lo (once per call); n4 = count of float4 groups
__global__ __launch_bounds__(256) void wsplit_k(const float* __restrict__ w,
    ushort* __restrict__ whi, ushort* __restrict__ wlo, int n4)
{
  int idx = blockIdx.x * 256 + threadIdx.x;
  if (idx >= n4) return;
  size_t i = (size_t)idx * 4;
  float4 v = *(const float4*)&w[i];
  ushort h0 = f2bf(v.x), h1 = f2bf(v.y), h2 = f2bf(v.z), h3 = f2bf(v.w);
  ushort l0 = f2bf(v.x - bf2f(h0)), l1 = f2bf(v.y - bf2f(h1));
  ushort l2 = f2bf(v.z - bf2f(h2)), l3 = f2bf(v.w - bf2f(h3));
  ushort4 hv = {h0, h1, h2, h3}, lv = {l0, l1, l2, l3};
  *(ushort4*)&whi[i] = hv;
  *(ushort4*)&wlo[i] = lv;
}

// fallback GRU gates (non-fused path), h updated in place; emits bf16 hi/lo split
__global__ __launch_bounds__(256) void gru_gates_k(const float* __restrict__ gx,
    const float* __restrict__ gh, float* __restrict__ h,
    ushort* __restrict__ hhi, ushort* __restrict__ hlo)
{
  int idx = blockIdx.x * 256 + threadIdx.x;   // B*H = 131072
  int b = idx >> 10, j = idx & 1023;
  const float* gxb = gx + (size_t)b * 3 * H;
  const float* ghb = gh + (size_t)b * 3 * H;
  float r = sigmoidf_(gxb[j] + ghb[j]);
  float z = sigmoidf_(gxb[H + j] + ghb[H + j]);
  float n = tanhf(gxb[2 * H + j] + r * ghb[2 * H + j]);
  float hn = (1.0f - z) * n + z * h[idx];
  h[idx] = hn;
  ushort hi = f2bf(hn);
  hhi[idx] = hi;
  hlo[idx] = f2bf(hn - bf2f(hi));
}

// ---------------- FUSED GRU (gemm x2 + gates) + piggybacked probs(t-1) ----------------
// Blocks 0..127: GRU. Block = 64 rows x 16 j-cols; computes all 6 gate tiles
// (xr,xz,xn over K=E; hr,hz,hn over K=H) into registers, then applies gate math and
// writes h_new (f32 + bf16 hi/lo) double-buffered. Gate float ordering identical to
// gru_gates_k: (accX + b_ih) + (accH + b_hh).
// Blocks 128..627: probs for step t-1 (logits/rowm/rowz of t-1 are still valid since
// dist(t) runs after this kernel). t=0: probs part idles; t=63 handled by tail launch.
__global__ __launch_bounds__(256) void gru_fused_k(
    const ushort* __restrict__ xhi, const ushort* __restrict__ xlo,
    const ushort* __restrict__ hhi_r, const ushort* __restrict__ hlo_r,
    const float* __restrict__ h_r,
    const ushort* __restrict__ wihhi, const ushort* __restrict__ wihlo,
    const ushort* __restrict__ whhhi, const ushort* __restrict__ whhlo,
    const float* __restrict__ b_ih, const float* __restrict__ b_hh,
    float* __restrict__ h_w, ushort* __restrict__ hhi_w, ushort* __restrict__ hlo_w,
    const float* __restrict__ logits, const float* __restrict__ rowm,
    const float* __restrict__ rowz, float* __restrict__ out, int t)
{
  if (blockIdx.x >= 128) {
    // ---------------- probs(t-1) ----------------
    if (t == 0) return;
    __shared__ float sm[B], sz[B];
    __shared__ float red[256];
    const int tid = threadIdx.x;
    if (tid < B) { sm[tid] = rowm[tid]; sz[tid] = rowz[tid]; }
    __syncthreads();
    const int pb = blockIdx.x - 128;
    const int v = pb * 64 + (tid & 63);
    const int bh = tid >> 6;
    float acc = 0.0f;
#pragma unroll 4
    for (int i = 0; i < 32; ++i) {
      int bb = bh * 32 + i;
      acc += expf((logits[(size_t)bb * V + v] - sm[bb]) - sz[bb]);
    }
    red[tid] = acc;
    __syncthreads();
    if (tid < 64) {
      float r = red[tid] + red[tid + 64] + red[tid + 128] + red[tid + 192];
      out[3 * BS + (size_t)(t - 1) * V + v] = r * (1.0f / 128.0f);
    }
    return;
  }

  // ---------------- GRU part ----------------
  __shared__ ushort Ah[2][64 * 32], Al[2][64 * 32];     // A tile (x or h_old) hi/lo
  __shared__ ushort Wh3[2][48 * 32], Wl3[2][48 * 32];   // 3 gate W tiles stacked
  const int tid = threadIdx.x;
  const int wave = tid >> 6, lane = tid & 63;
  const int l15 = lane & 15, q = lane >> 4;
  const int blk = blockIdx.x;
  const int mblk = (blk & 1) * 64;
  const int jb = (blk >> 1) * 16;                       // j base in [0,H)

  // staging geometry (per wave): A seg = rows wave*16..+16; W seg = gate `wave` (wave<3)
  const int atr = wave * 16 + (lane >> 2);              // A tile row staged by this lane
  const int sq8 = ((lane & 3) ^ ((lane >> 3) & 3)) * 8; // swizzled k-quad (x8 ushorts)
  const int wgr = jb + (lane >> 2);                     // W row within gate block
  const int aBase = wave * 512;                         // LDS ushort base (A seg)
  const int wBase = wave * 512;                         // LDS ushort base (W seg, wave<3)

  f32x4 accX[3] = {}, accH[3] = {};

  // ---- loop 1: x @ w_ih^T (K = E = 512) ----
  {
    const size_t aRow = (size_t)(mblk + atr) * E + sq8;
    const size_t wRow = (size_t)(wave * H + wgr) * E + sq8;   // w_ih row = gate*H + j
#define STAGE1(bf, kk) {                                           \
      gload16(&xhi[aRow + (kk)], &Ah[bf][aBase]);                  \
      gload16(&xlo[aRow + (kk)], &Al[bf][aBase]);                  \
      if (wave < 3) {                                              \
        gload16(&wihhi[wRow + (kk)], &Wh3[bf][wBase]);             \
        gload16(&wihlo[wRow + (kk)], &Wl3[bf][wBase]);             \
      } }
    STAGE1(0, 0);
    asm volatile("s_waitcnt vmcnt(0)" ::: "memory");
    __builtin_amdgcn_sched_barrier(0);
    __builtin_amdgcn_s_barrier();
    int buf = 0;
    for (int k0 = 0; k0 < E; k0 += 32, buf ^= 1) {
      if (k0 + 32 < E) STAGE1(buf ^ 1, k0 + 32);
      const int ar = wave * 16 + l15;
      const int aoff = ar * 32 + ((q ^ ((ar >> 1) & 3)) * 8);
      short8 ah = *(const short8*)&Ah[buf][aoff];
      short8 al = *(const short8*)&Al[buf][aoff];
#pragma unroll
      for (int g = 0; g < 3; ++g) {
        const int wr = g * 16 + l15;
        const int woff = wr * 32 + ((q ^ ((wr >> 1) & 3)) * 8);
        short8 wh = *(const short8*)&Wh3[buf][woff];
        short8 wl = *(const short8*)&Wl3[buf][woff];
        accX[g] = __builtin_amdgcn_mfma_f32_16x16x32_bf16(ah, wh, accX[g], 0, 0, 0);
        accX[g] = __builtin_amdgcn_mfma_f32_16x16x32_bf16(al, wh, accX[g], 0, 0, 0);
        accX[g] = __builtin_amdgcn_mfma_f32_16x16x32_bf16(ah, wl, accX[g], 0, 0, 0);
      }
      asm volatile("s_waitcnt vmcnt(0)" ::: "memory");
      __builtin_amdgcn_sched_barrier(0);
      __builtin_amdgcn_s_barrier();
    }
#undef STAGE1
  }

  // ---- loop 2: h_old @ w_hh^T (K = H = 1024) ----
  {
    const size_t aRow = (size_t)(mblk + atr) * H + sq8;
    const size_t wRow = (size_t)(wave * H + wgr) * H + sq8;   // w_hh row = gate*H + j
#define STAGE2(bf, kk) {                                           \
      gload16(&hhi_r[aRow + (kk)], &Ah[bf][aBase]);                \
      gload16(&hlo_r[aRow + (kk)], &Al[bf][aBase]);                \
      if (wave < 3) {                                              \
        gload16(&whhhi[wRow + (kk)], &Wh3[bf][wBase]);             \
        gload16(&whhlo[wRow + (kk)], &Wl3[bf][wBase]);             \
      } }
    STAGE2(0, 0);
    asm volatile("s_waitcnt vmcnt(0)" ::: "memory");
    __builtin_amdgcn_sched_barrier(0);
    __builtin_amdgcn_s_barrier();
    int buf = 0;
    for (int k0 = 0; k0 < H; k0 += 32, buf ^= 1) {
      if (k0 + 32 < H) STAGE2(buf ^ 1, k0 + 32);
      const int ar = wave * 16 + l15;
      const int aoff = ar * 32 + ((q ^ ((ar >> 1) & 3)) * 8);
      short8 ah = *(const short8*)&Ah[buf][aoff];
      short8 al = *(const short8*)&Al[buf][aoff];
#pragma unroll
      for (int g = 0; g < 3; ++g) {
        const int wr = g * 16 + l15;
        const int woff = wr * 32 + ((q ^ ((wr >> 1) & 3)) * 8);
        short8 wh = *(const short8*)&Wh3[buf][woff];
        short8 wl = *(const short8*)&Wl3[buf][woff];
        accH[g] = __builtin_amdgcn_mfma_f32_16x16x32_bf16(ah, wh, accH[g], 0, 0, 0);
        accH[g] = __builtin_amdgcn_mfma_f32_16x16x32_bf16(al, wh, accH[g], 0, 0, 0);
        accH[g] = __builtin_amdgcn_mfma_f32_16x16x32_bf16(ah, wl, accH[g], 0, 0, 0);
      }
      asm volatile("s_waitcnt vmcnt(0)" ::: "memory");
      __builtin_amdgcn_sched_barrier(0);
      __builtin_amdgcn_s_barrier();
    }
#undef STAGE2
  }

  // ---- gate epilogue: identical float ordering to gru_gates_k ----
  const int colj = jb + l15;
  float bihv[3], bhhv[3];
#pragma unroll
  for (int g = 0; g < 3; ++g) {
    bihv[g] = b_ih[g * H + colj];
    bhhv[g] = b_hh[g * H + colj];
  }
#pragma unroll
  for (int reg = 0; reg < 4; ++reg) {
    const int row = mblk + wave * 16 + q * 4 + reg;
    const size_t oi = (size_t)row * H + colj;
    float gxr = accX[0][reg] + bihv[0], ghr = accH[0][reg] + bhhv[0];
    float gxz = accX[1][reg] + bihv[1], ghz = accH[1][reg] + bhhv[1];
    float gxn = accX[2][reg] + bihv[2], ghn = accH[2][reg] + bhhv[2];
    float r = sigmoidf_(gxr + ghr);
    float z = sigmoidf_(gxz + ghz);
    float n = tanhf(gxn + r * ghn);
    float hn = (1.0f - z) * n + z * h_r[oi];
    h_w[oi] = hn;
    ushort hi = f2bf(hn);
    hhi_w[oi] = hi;
    hlo_w[oi] = f2bf(hn - bf2f(hi));
  }
}

// ---------------- MFMA bf16x3 dist GEMM with FUSED sampling partials ----------------
// (byte-identical to verified R5 kernel)
__global__ __launch_bounds__(512) void gemm_dist_mfma(const ushort* __restrict__ hhi,
    const ushort* __restrict__ hlo, const ushort* __restrict__ whi,
    const ushort* __restrict__ wlo, const float* __restrict__ b_dist,
    float* __restrict__ logits,
    float* __restrict__ pm, float* __restrict__ ps,
    float* __restrict__ pbest, int* __restrict__ pidx,
    uint32_t k1a, uint32_t k1b, uint32_t k2a, uint32_t k2b)
{
  __shared__ ushort Ah[2][128 * 32], Al[2][128 * 32], Wh[2][128 * 32], Wl[2][128 * 32];
  __shared__ float rm[2 * 128], rs[2 * 128], rb_[2 * 128];
  __shared__ int   ri[2 * 128];
  __shared__ uint32_t sdraw[128];
  const int tid = threadIdx.x;
  const int wave = tid >> 6, lane = tid & 63;
  const int wm = (wave & 3) * 32;
  const int wn = (wave >> 2) * 64;
  const int nblk = blockIdx.x * 128;
  const int l15 = lane & 15;
  const int q = lane >> 4;

  if (tid < 128)
    sdraw[tid] = (bits_to_unif(tf_bits32(k1a, k1b, (uint32_t)tid)) <= 0.05f) ? 1u : 0u;

  const int sr = tid >> 2;
  const int gq8 = ((tid & 3) ^ ((sr >> 1) & 3)) * 8;
  const size_t arow = (size_t)sr * 1024 + gq8;
  const size_t wrow = (size_t)(nblk + sr) * 1024 + gq8;
  const int wbase = wave * 512;

#define DIST_STAGE(bf, kk) {                                   \
    gload16(&hhi[arow + (kk)], &Ah[bf][wbase]);                \
    gload16(&hlo[arow + (kk)], &Al[bf][wbase]);                \
    gload16(&whi[wrow + (kk)], &Wh[bf][wbase]);                \
    gload16(&wlo[wrow + (kk)], &Wl[bf][wbase]);                \
  }

  f32x4 acc[2][4] = {};

  DIST_STAGE(0, 0);

  int buf = 0;
  for (int k0 = 0; k0 < 1024; k0 += 32, buf ^= 1) {
    const bool more = (k0 + 32 < 1024);
    if (more) {
      DIST_STAGE(buf ^ 1, k0 + 32);
      asm volatile("s_waitcnt vmcnt(4)" ::: "memory");
    } else {
      asm volatile("s_waitcnt vmcnt(0)" ::: "memory");
    }
    __builtin_amdgcn_sched_barrier(0);
    __builtin_amdgcn_s_barrier();
    __builtin_amdgcn_sched_barrier(0);

    short8 ah[2], al[2], wh[4], wl[4];
#pragma unroll
    for (int mt = 0; mt < 2; ++mt) {
      int row = wm + mt * 16 + l15;
      int off = row * 32 + ((q ^ ((row >> 1) & 3)) * 8);
      ah[mt] = *(const short8*)&Ah[buf][off];
      al[mt] = *(const short8*)&Al[buf][off];
    }
#pragma unroll
    for (int nt = 0; nt < 4; ++nt) {
      int row = wn + nt * 16 + l15;
      int off = row * 32 + ((q ^ ((row >> 1) & 3)) * 8);
      wh[nt] = *(const short8*)&Wh[buf][off];
      wl[nt] = *(const short8*)&Wl[buf][off];
    }
#pragma unroll
    for (int mt = 0; mt < 2; ++mt)
#pragma unroll
      for (int nt = 0; nt < 4; ++nt) {
        acc[mt][nt] = __builtin_amdgcn_mfma_f32_16x16x32_bf16(ah[mt], wh[nt], acc[mt][nt], 0, 0, 0);
        acc[mt][nt] = __builtin_amdgcn_mfma_f32_16x16x32_bf16(al[mt], wh[nt], acc[mt][nt], 0, 0, 0);
        acc[mt][nt] = __builtin_amdgcn_mfma_f32_16x16x32_bf16(ah[mt], wl[nt], acc[mt][nt], 0, 0, 0);
      }

    __builtin_amdgcn_s_barrier();
  }
#undef DIST_STAGE

  float bv[4];
#pragma unroll
  for (int nt = 0; nt < 4; ++nt) bv[nt] = b_dist[nblk + wn + nt * 16 + l15];

  const float LOGU = -logf((float)V);
#pragma unroll
  for (int mt = 0; mt < 2; ++mt) {
#pragma unroll
    for (int reg = 0; reg < 4; ++reg) {
      const int r = wm + mt * 16 + q * 4 + reg;     // batch row
      const bool draw = sdraw[r] != 0u;
      float m0 = NEG_HUGE, s0 = 0.0f, best = NEG_HUGE;
      int bi = 2147483647;
#pragma unroll
      for (int nt = 0; nt < 4; ++nt) {
        const int col = nblk + wn + nt * 16 + l15;
        float a = acc[mt][nt][reg] + bv[nt];
        logits[(size_t)r * V + col] = a;
        if (a > m0) { s0 = s0 * expf(m0 - a) + 1.0f; m0 = a; } else { s0 += expf(a - m0); }
        uint32_t bits = tf_bits32(k2a, k2b, (uint32_t)(r * V + col));
        float g = -logf(-logf(bits_to_unif(bits)));
        float key = draw ? (LOGU + g) : (a + g);
        if (key > best) { best = key; bi = col; }
      }
#pragma unroll
      for (int off = 1; off < 16; off <<= 1) {
        float mo = __shfl_xor(m0, off);
        float so = __shfl_xor(s0, off);
        float M = fmaxf(m0, mo);
        s0 = s0 * expf(m0 - M) + so * expf(mo - M);
        m0 = M;
        float bo = __shfl_xor(best, off);
        int io = __shfl_xor(bi, off);
        if (bo > best || (bo == best && io < bi)) { best = bo; bi = io; }
      }
      if (l15 == 0) {
        const int slot = (wave >> 2) * 128 + r;
        rm[slot] = m0; rs[slot] = s0; rb_[slot] = best; ri[slot] = bi;
      }
    }
  }
  __syncthreads();
  if (tid < 128) {
    float ma = rm[tid], sa = rs[tid], mb = rm[128 + tid], sb = rs[128 + tid];
    float M = fmaxf(ma, mb);
    float s = sa * expf(ma - M) + sb * expf(mb - M);
    pm[tid * PSTRIDE + blockIdx.x] = M;
    ps[tid * PSTRIDE + blockIdx.x] = s;
    float va = rb_[tid], vb = rb_[128 + tid];
    int ia = ri[tid], ib = ri[128 + tid];
    if (vb > va || (vb == va && ib < ia)) { va = vb; ia = ib; }
    pbest[tid * PSTRIDE + blockIdx.x] = va;
    pidx[tid * PSTRIDE + blockIdx.x] = ia;
  }
}

// ---------------- MFMA bf16x3 64x64-tile GEMM (GRU fallback when fused unusable) ----
__device__ void gemm64_bf16x3(const ushort* __restrict__ Ahi_g, const ushort* __restrict__ Alo_g,
    const ushort* __restrict__ Whi_g, const ushort* __restrict__ Wlo_g,
    const float* __restrict__ bias, float* __restrict__ C,
    int N, int K, int mblk, int nblk)
{
  __shared__ ushort Ah[2][64 * 32], Al[2][64 * 32], Wh[2][64 * 32], Wl[2][64 * 32];
  const int tid = threadIdx.x;
  const int wave = tid >> 6, lane = tid & 63;
  const int wm = (wave & 1) * 32, wn = (wave >> 1) * 32;
  const int l15 = lane & 15, q = lane >> 4;

  const int sr = tid >> 2;
  const int gq8 = ((tid & 3) ^ ((sr >> 1) & 3)) * 8;
  const size_t arow = (size_t)(mblk + sr) * K + gq8;
  const size_t wrow = (size_t)(nblk + sr) * K + gq8;
  const int wbase = wave * 512;

#define GRU_STAGE(bf, kk) {                                    \
    gload16(&Ahi_g[arow + (kk)], &Ah[bf][wbase]);              \
    gload16(&Alo_g[arow + (kk)], &Al[bf][wbase]);              \
    gload16(&Whi_g[wrow + (kk)], &Wh[bf][wbase]);              \
    gload16(&Wlo_g[wrow + (kk)], &Wl[bf][wbase]);              \
  }

  f32x4 acc[2][2] = {};

  GRU_STAGE(0, 0);
  asm volatile("s_waitcnt vmcnt(0)" ::: "memory");
  __builtin_amdgcn_sched_barrier(0);
  __builtin_amdgcn_s_barrier();

  int buf = 0;
  for (int k0 = 0; k0 < K; k0 += 32, buf ^= 1) {
    if (k0 + 32 < K) GRU_STAGE(buf ^ 1, k0 + 32);

    short8 ah[2], al[2], wh[2], wl[2];
#pragma unroll
    for (int mt = 0; mt < 2; ++mt) {
      int row = wm + mt * 16 + l15;
      int off = row * 32 + ((q ^ ((row >> 1) & 3)) * 8);
      ah[mt] = *(const short8*)&Ah[buf][off];
      al[mt] = *(const short8*)&Al[buf][off];
    }
#pragma unroll
    for (int nt = 0; nt < 2; ++nt) {
      int row = wn + nt * 16 + l15;
      int off = row * 32 + ((q ^ ((row >> 1) & 3)) * 8);
      wh[nt] = *(const short8*)&Wh[buf][off];
      wl[nt] = *(const short8*)&Wl[buf][off];
    }
#pragma unroll
    for (int mt = 0; mt < 2; ++mt)
#pragma unroll
      for (int nt = 0; nt < 2; ++nt) {
        acc[mt][nt] = __builtin_amdgcn_mfma_f32_16x16x32_bf16(ah[mt], wh[nt], acc[mt][nt], 0, 0, 0);
        acc[mt][nt] = __builtin_amdgcn_mfma_f32_16x16x32_bf16(al[mt], wh[nt], acc[mt][nt], 0, 0, 0);
        acc[mt][nt] = __builtin_amdgcn_mfma_f32_16x16x32_bf16(ah[mt], wl[nt], acc[mt][nt], 0, 0, 0);
      }

    asm volatile("s_waitcnt vmcnt(0)" ::: "memory");
    __builtin_amdgcn_sched_barrier(0);
    __builtin_amdgcn_s_barrier();
  }
#undef GRU_STAGE

#pragma unroll
  for (int nt = 0; nt < 2; ++nt) {
    int col = nblk + wn + nt * 16 + l15;
    float bv = bias[col];
#pragma unroll
    for (int mt = 0; mt < 2; ++mt) {
      int rbase = mblk + wm + mt * 16 + (lane >> 4) * 4;
#pragma unroll
      for (int reg = 0; reg < 4; ++reg)
        C[(size_t)(rbase + reg) * N + col] = acc[mt][nt][reg] + bv;
    }
  }
}

__global__ __launch_bounds__(256) void gemm_gru_mfma(
    const ushort* __restrict__ xhi, const ushort* __restrict__ xlo,
    const ushort* __restrict__ hhi, const ushort* __restrict__ hlo,
    const ushort* __restrict__ wihhi, const ushort* __restrict__ wihlo,
    const ushort* __restrict__ whhhi, const ushort* __restrict__ whhlo,
    const float* __restrict__ b_ih, const float* __restrict__ b_hh,
    float* __restrict__ gx, float* __restrict__ gh)
{
  int b = blockIdx.x;
  if (b < 96) {
    int mblk = (b & 1) * 64, nblk = (b >> 1) * 64;
    gemm64_bf16x3(xhi, xlo, wihhi, wihlo, b_ih, gx, 3 * H, E, mblk, nblk);
  } else {
    b -= 96;
    int mblk = (b & 1) * 64, nblk = (b >> 1) * 64;
    gemm64_bf16x3(hhi, hlo, whhhi, whhlo, b_hh, gh, 3 * H, H, mblk, nblk);
  }
}

// init: h = 0 (and its bf16 splits), x = broadcast emb[0] (and its bf16 splits)
__global__ __launch_bounds__(256) void init_k(const float* __restrict__ emb,
    float* __restrict__ h, float* __restrict__ x,
    ushort* __restrict__ hhi, ushort* __restrict__ hlo,
    ushort* __restrict__ xhi, ushort* __restrict__ xlo)
{
  int i = blockIdx.x * 256 + threadIdx.x;   // grid covers B*H
  if (i < B * H) { h[i] = 0.0f; hhi[i] = 0; hlo[i] = 0; }
  if (i < B * E) {
    float v = emb[i & (E - 1)];
    x[i] = v;
    ushort hi = f2bf(v);
    xhi[i] = hi;
    xlo[i] = f2bf(v - bf2f(hi));
  }
}

// fallback pass (f32 dist path only)
__global__ __launch_bounds__(256) void sample_partial_k(const float* __restrict__ logits,
    float* __restrict__ pm, float* __restrict__ ps,
    float* __restrict__ pbest, int* __restrict__ pidx,
    uint32_t k1a, uint32_t k1b, uint32_t k2a, uint32_t k2b)
{
  const int b = blockIdx.x & 127, chunk = blockIdx.x >> 7;
  const int tid = threadIdx.x;
  const bool draw = bits_to_unif(tf_bits32(k1a, k1b, (uint32_t)b)) <= 0.05f;
  const float LOGU = -logf((float)V);
  const int vbeg = chunk * CHUNK, vend = vbeg + CHUNK;
  float m0 = -INFINITY, s0 = 0.0f, best = -INFINITY;
  int bi = 2147483647;
  for (int v = vbeg + tid; v < vend; v += 256) {
    float a = logits[(size_t)b * V + v];
    if (a > m0) { s0 = s0 * expf(m0 - a) + 1.0f; m0 = a; } else { s0 += expf(a - m0); }
    uint32_t bits = tf_bits32(k2a, k2b, (uint32_t)(b * V + v));
    float g = -logf(-logf(bits_to_unif(bits)));
    float key = draw ? (LOGU + g) : (a + g);
    if (key > best) { best = key; bi = v; }
  }
  __shared__ float shm[256], shs[256], sv[256];
  __shared__ int si[256];
  shm[tid] = m0; shs[tid] = s0; sv[tid] = best; si[tid] = bi;
  __syncthreads();
  for (int off = 128; off > 0; off >>= 1) {
    if (tid < off) {
      float ma = shm[tid], sa = shs[tid];
      float mb = shm[tid + off], sb = shs[tid + off];
      float M = fmaxf(ma, mb);
      shm[tid] = M;
      shs[tid] = sa * expf(ma - M) + sb * expf(mb - M);
      float va = sv[tid], vb = sv[tid + off];
      int ia = si[tid], ib = si[tid + off];
      if (vb > va || (vb == va && ib < ia)) { sv[tid] = vb; si[tid] = ib; }
    }
    __syncthreads();
  }
  if (tid == 0) {
    pm[b * PSTRIDE + chunk] = shm[0]; ps[b * PSTRIDE + chunk] = shs[0];
    pbest[b * PSTRIDE + chunk] = sv[0]; pidx[b * PSTRIDE + chunk] = si[0];
  }
}

// fused final: block b = row b, 128 threads
__global__ __launch_bounds__(128) void sample_final_gather_k(const float* __restrict__ logits,
    const float* __restrict__ pm, const float* __restrict__ ps,
    const float* __restrict__ pbest, const int* __restrict__ pidx,
    float* __restrict__ rowm, float* __restrict__ rowz, int* __restrict__ samp,
    const float* __restrict__ emb, float* __restrict__ x,
    ushort* __restrict__ xhi, ushort* __restrict__ xlo,
    float* __restrict__ out, int t, uint32_t k1a, uint32_t k1b, int nchunk)
{
  __shared__ float shm[128], shs[128], shb[128];
  __shared__ int shi[128];
  __shared__ int sh_idx;
  const int b = blockIdx.x, tid = threadIdx.x;
  float m0 = NEG_HUGE, s0 = 0.0f, best = NEG_HUGE;
  int bi = 2147483647;
  for (int c = tid; c < nchunk; c += 128) {
    float ma = pm[b * PSTRIDE + c], sa = ps[b * PSTRIDE + c];
    float M = fmaxf(m0, ma);
    s0 = s0 * expf(m0 - M) + sa * expf(ma - M);
    m0 = M;
    float v = pbest[b * PSTRIDE + c];
    int ix = pidx[b * PSTRIDE + c];
    if (v > best || (v == best && ix < bi)) { best = v; bi = ix; }
  }
  shm[tid] = m0; shs[tid] = s0; shb[tid] = best; shi[tid] = bi;
  __syncthreads();
  for (int off = 64; off > 0; off >>= 1) {
    if (tid < off) {
      float ma = shm[tid], sa = shs[tid];
      float mb = shm[tid + off], sb = shs[tid + off];
      float M = fmaxf(ma, mb);
      shm[tid] = M;
      shs[tid] = sa * expf(ma - M) + sb * expf(mb - M);
      float va = shb[tid], vb = shb[tid + off];
      int ia = shi[tid], ib = shi[tid + off];
      if (vb > va || (vb == va && ib < ia)) { shb[tid] = vb; shi[tid] = ib; }
    }
    __syncthreads();
  }
  if (tid == 0) {
    float mrow = shm[0];
    float z0 = logf(shs[0]);
    int idx = shi[0];
    rowm[b] = mrow; rowz[b] = z0;
    float lp = (logits[(size_t)b * V + idx] - mrow) - z0;
    bool draw = bits_to_unif(tf_bits32(k1a, k1b, (uint32_t)b)) <= 0.05f;
    float corr = 1.0f;
    if (draw) {
      const float LOGU = -logf((float)V);
      float onp = fminf(fmaxf(expf(lp), 1e-8f), 1.0f);
      float offp = fminf(fmaxf(expf(LOGU), 1e-8f), 1.0f);
      corr = onp / offp;
    }
    out[b * S + t] = (float)idx;
    out[BS + b * S + t] = corr;
    out[2 * BS + b * S + t] = lp;
    samp[b] = idx;
    sh_idx = idx;
  }
  __syncthreads();
  const int row = sh_idx;
  float4 v = *(const float4*)&emb[(size_t)row * E + tid * 4];
  *(float4*)&x[(size_t)b * E + tid * 4] = v;
  ushort h0 = f2bf(v.x), h1 = f2bf(v.y), h2 = f2bf(v.z), h3 = f2bf(v.w);
  ushort l0 = f2bf(v.x - bf2f(h0)), l1 = f2bf(v.y - bf2f(h1));
  ushort l2 = f2bf(v.z - bf2f(h2)), l3 = f2bf(v.w - bf2f(h3));
  ushort4 hv = {h0, h1, h2, h3}, lv = {l0, l1, l2, l3};
  *(ushort4*)&xhi[(size_t)b * E + tid * 4] = hv;
  *(ushort4*)&xlo[(size_t)b * E + tid * 4] = lv;
}

// standalone probs (fallback path + tail step in fused path)
__global__ __launch_bounds__(256) void probs_k(const float* __restrict__ logits,
    const float* __restrict__ rowm, const float* __restrict__ rowz,
    float* __restrict__ out, int t)
{
  __shared__ float sm[B], sz[B];
  __shared__ float red[256];
  const int tid = threadIdx.x;
  if (tid < B) { sm[tid] = rowm[tid]; sz[tid] = rowz[tid]; }
  __syncthreads();
  const int v = blockIdx.x * 64 + (tid & 63);
  const int bh = tid >> 6;
  float acc = 0.0f;
#pragma unroll 4
  for (int i = 0; i < 32; ++i) {
    int b = bh * 32 + i;
    acc += expf((logits[(size_t)b * V + v] - sm[b]) - sz[b]);
  }
  red[tid] = acc;
  __syncthreads();
  if (tid < 64) {
    float r = red[tid] + red[tid + 64] + red[tid + 128] + red[tid + 192];
    out[3 * BS + (size_t)t * V + v] = r * (1.0f / 128.0f);
  }
}

extern "C" void kernel_launch(void* const* d_in, const int* in_sizes, int n_in,
                              void* d_out, int out_size, void* d_ws, size_t ws_size,
                              hipStream_t stream) {
  (void)in_sizes; (void)n_in; (void)out_size;
  const float* emb    = (const float*)d_in[0];
  const float* w_ih   = (const float*)d_in[1];
  const float* w_hh   = (const float*)d_in[2];
  const float* b_ih   = (const float*)d_in[3];
  const float* b_hh   = (const float*)d_in[4];
  const float* w_dist = (const float*)d_in[5];
  const float* b_dist = (const float*)d_in[6];
  float* out = (float*)d_out;

  float* ws = (float*)d_ws;
  float* h      = ws;                      // B*H   (h slot 0)
  float* x      = h + B * H;               // B*E
  float* gx     = x + B * E;               // B*3H  (fused mode: aliased as h slot 1)
  float* gh     = gx + B * 3 * H;          // B*3H
  float* logits = gh + B * 3 * H;          // B*V
  float* pm     = logits + (size_t)B * V;  // B*PSTRIDE
  float* ps     = pm + B * PSTRIDE;
  float* pbest  = ps + B * PSTRIDE;
  int*   pidx   = (int*)(pbest + B * PSTRIDE);
  float* rowm   = (float*)(pidx + B * PSTRIDE);
  float* rowz   = rowm + B;
  int*   samp   = (int*)(rowz + B);
  ushort* hhi   = (ushort*)(samp + B);                 // B*H  (split slot 0)
  ushort* hlo   = hhi + (size_t)B * H;                 // B*H
  // dist split region
  ushort* whi   = hlo + (size_t)B * H;                 // V*H
  ushort* wlo   = whi + (size_t)V * H;                 // V*H
  // gru split region
  ushort* xhi   = wlo + (size_t)V * H;                 // B*E
  ushort* xlo   = xhi + (size_t)B * E;                 // B*E
  ushort* wihhi = xlo + (size_t)B * E;                 // 3H*E
  ushort* wihlo = wihhi + (size_t)3 * H * E;           // 3H*E
  ushort* whhhi = wihlo + (size_t)3 * H * E;           // 3H*H
  ushort* whhlo = whhhi + (size_t)3 * H * H;           // 3H*H

  // fused-mode h slot 1, aliased into the (then-unused) gx region:
  // B*H f32 + 2 * B*H ushort = 262144 f32 <= gx's 393216 f32.
  float*  h1   = gx;
  ushort* hhi1 = (ushort*)(gx + B * H);
  ushort* hlo1 = hhi1 + (size_t)B * H;

  size_t need_dist = (size_t)((char*)xhi - (char*)d_ws);
  size_t need_gru  = (size_t)((char*)(whhlo + (size_t)3 * H * H) - (char*)d_ws);
  const bool use_dist_mfma = ws_size >= need_dist;
  const bool use_gru_mfma  = ws_size >= need_gru;
  const bool fused = use_dist_mfma && use_gru_mfma;

  init_k<<<512, 256, 0, stream>>>(emb, h, x, hhi, hlo, xhi, xlo);
  if (use_dist_mfma)
    wsplit_k<<<(V * H / 4 + 255) / 256, 256, 0, stream>>>(w_dist, whi, wlo, V * H / 4);
  if (use_gru_mfma) {
    wsplit_k<<<(3 * H * E / 4 + 255) / 256, 256, 0, stream>>>(w_ih, wihhi, wihlo, 3 * H * E / 4);
    wsplit_k<<<(3 * H * H / 4 + 255) / 256, 256, 0, stream>>>(w_hh, whhhi, whhlo, 3 * H * H / 4);
  }

  float*  hF[2]  = {h, h1};
  ushort* hHI[2] = {hhi, hhi1};
  ushort* hLO[2] = {hlo, hlo1};

  const uint32_t base0 = 0u, base1 = 42u;   // jax.random.key(42)
  for (int t = 0; t < S; ++t) {
    uint32_t f0 = 0u, f1 = (uint32_t)t;
    tf2x32(base0, base1, f0, f1);                            // k_t = fold_in(base, t)
    uint32_t k1a = 0u, k1b = 0u; tf2x32(f0, f1, k1a, k1b);   // k1 = enc(0,0)
    uint32_t k2a = 0u, k2b = 1u; tf2x32(f0, f1, k2a, k2b);   // k2 = enc(0,1)

    if (fused) {
      const int rd = t & 1, wr = rd ^ 1;
      gru_fused_k<<<628, 256, 0, stream>>>(xhi, xlo, hHI[rd], hLO[rd], hF[rd],
                                           wihhi, wihlo, whhhi, whhlo, b_ih, b_hh,
                                           hF[wr], hHI[wr], hLO[wr],
                                           logits, rowm, rowz, out, t);
      gemm_dist_mfma<<<250, 512, 0, stream>>>(hHI[wr], hLO[wr], whi, wlo, b_dist, logits,
                                              pm, ps, pbest, pidx, k1a, k1b, k2a, k2b);
      sample_final_gather_k<<<128, 128, 0, stream>>>(logits, pm, ps, pbest, pidx,
                                                     rowm, rowz, samp, emb, x, xhi, xlo,
                                                     out, t, k1a, k1b, 250);
    } else {
      if (use_gru_mfma)
        gemm_gru_mfma<<<192, 256, 0, stream>>>(xhi, xlo, hhi, hlo, wihhi, wihlo,
                                               whhhi, whhlo, b_ih, b_hh, gx, gh);
      else
        gemm_gru_k<<<192, 256, 0, stream>>>(x, h, w_ih, w_hh, b_ih, b_hh, gx, gh);
      gru_gates_k<<<512, 256, 0, stream>>>(gx, gh, h, hhi, hlo);
      int nchunk;
      if (use_dist_mfma) {
        gemm_dist_mfma<<<250, 512, 0, stream>>>(hhi, hlo, whi, wlo, b_dist, logits,
                                                pm, ps, pbest, pidx, k1a, k1b, k2a, k2b);
        nchunk = 250;
      } else {
        gemm_dist_k<<<500, 256, 0, stream>>>(h, w_dist, b_dist, logits);
        sample_partial_k<<<1024, 256, 0, stream>>>(logits, pm, ps, pbest, pidx,
                                                   k1a, k1b, k2a, k2b);
        nchunk = NCHUNK;
      }
      sample_final_gather_k<<<128, 128, 0, stream>>>(logits, pm, ps, pbest, pidx,
                                                     rowm, rowz, samp, emb, x, xhi, xlo,
                                                     out, t, k1a, k1b, nchunk);
      probs_k<<<500, 256, 0, stream>>>(logits, rowm, rowz, out, t);
    }
  }
  if (fused)
    probs_k<<<500, 256, 0, stream>>>(logits, rowm, rowz, out, S - 1);
}